// Round 2
// baseline (2074.346 us; speedup 1.0000x reference)
//
#include <hip/hip_runtime.h>
#include <math.h>

// ---------- types / helpers ----------
typedef unsigned short u16;
typedef short short8 __attribute__((ext_vector_type(8)));
typedef float f32x4 __attribute__((ext_vector_type(4)));

#define DEV static __device__ __forceinline__

DEV float bf2f(u16 h) { union { unsigned int u; float f; } v; v.u = ((unsigned int)h) << 16; return v.f; }
DEV u16 f2bf(float f) {
  union { float f; unsigned int u; } v; v.f = f;
  unsigned int r = v.u + 0x7FFFu + ((v.u >> 16) & 1u);  // RNE
  return (u16)(r >> 16);
}

DEV void gl_lds16(const void* g, void* l) {
  __builtin_amdgcn_global_load_lds(
      (const __attribute__((address_space(1))) unsigned int*)g,
      (__attribute__((address_space(3))) unsigned int*)l, 16, 0, 0);
}

// ---------- RMSNorm: f32 [2048][4096] -> bf16 (optionally split hi/lo) ----------
template <bool SPLIT>
__global__ __launch_bounds__(256) void rmsnorm_kernel(
    const float* __restrict__ x, const float* __restrict__ g,
    u16* __restrict__ oh, u16* __restrict__ ol) {
  int row = blockIdx.x, t = threadIdx.x;
  const float* xr = x + (size_t)row * 4096;
  float4 vals[4];
  float s = 0.f;
#pragma unroll
  for (int i = 0; i < 4; i++) {
    vals[i] = ((const float4*)xr)[t + i * 256];
    s += vals[i].x * vals[i].x + vals[i].y * vals[i].y + vals[i].z * vals[i].z + vals[i].w * vals[i].w;
  }
#pragma unroll
  for (int m = 1; m < 64; m <<= 1) s += __shfl_xor(s, m);
  __shared__ float red[4];
  if ((t & 63) == 0) red[t >> 6] = s;
  __syncthreads();
  s = red[0] + red[1] + red[2] + red[3];
  float rinv = rsqrtf(s * (1.f / 4096.f) + 1.1920929e-07f);
#pragma unroll
  for (int i = 0; i < 4; i++) {
    float4 gv = ((const float4*)g)[t + i * 256];
    float4 v = vals[i];
    float f[4] = {v.x * rinv * gv.x, v.y * rinv * gv.y, v.z * rinv * gv.z, v.w * rinv * gv.w};
    ushort4 rh, rl;
    u16* hp = (u16*)&rh; u16* lp = (u16*)&rl;
#pragma unroll
    for (int j = 0; j < 4; j++) {
      u16 hi = f2bf(f[j]);
      hp[j] = hi;
      if (SPLIT) lp[j] = f2bf(f[j] - bf2f(hi));
    }
    ((ushort4*)(oh + (size_t)row * 4096))[t + i * 256] = rh;
    if (SPLIT) ((ushort4*)(ol + (size_t)row * 4096))[t + i * 256] = rl;
  }
}

// ---------- transpose-convert: w f32 [K][N] -> wT bf16 [N][K] ----------
__global__ void tconv_kernel(const float* __restrict__ in, u16* __restrict__ out, int K, int N) {
  __shared__ float tile[32][33];
  int k0 = blockIdx.y * 32, n0 = blockIdx.x * 32;
  int tx = threadIdx.x, ty = threadIdx.y;  // (32,8)
#pragma unroll
  for (int i = 0; i < 4; i++)
    tile[ty + 8 * i][tx] = in[(size_t)(k0 + ty + 8 * i) * N + n0 + tx];
  __syncthreads();
#pragma unroll
  for (int i = 0; i < 4; i++) {
    int n = ty + 8 * i;
    out[(size_t)(n0 + n) * K + k0 + tx] = f2bf(tile[tx][n]);
  }
}

// ---------- transpose-convert split: w f32 [K][N] -> hi/lo bf16 [N][K] ----------
__global__ void tconv_split_kernel(const float* __restrict__ in, u16* __restrict__ oh,
                                   u16* __restrict__ ol, int K, int N) {
  __shared__ float tile[32][33];
  int k0 = blockIdx.y * 32, n0 = blockIdx.x * 32;
  int tx = threadIdx.x, ty = threadIdx.y;  // (32,8)
#pragma unroll
  for (int i = 0; i < 4; i++)
    tile[ty + 8 * i][tx] = in[(size_t)(k0 + ty + 8 * i) * N + n0 + tx];
  __syncthreads();
#pragma unroll
  for (int i = 0; i < 4; i++) {
    int n = ty + 8 * i;
    float f = tile[tx][n];
    u16 hi = f2bf(f);
    size_t idx = (size_t)(n0 + n) * K + k0 + tx;
    oh[idx] = hi;
    ol[idx] = f2bf(f - bf2f(hi));
  }
}

// ---------- bf16 transpose v [2048][4096] -> vT [32][128][2048] ----------
__global__ void vtrans_kernel(const u16* __restrict__ v, u16* __restrict__ vt) {
  __shared__ u16 tile[32][33];
  int s0 = blockIdx.x * 32, d0 = blockIdx.y * 32, hd = blockIdx.z;
  int tx = threadIdx.x, ty = threadIdx.y;  // (32,8)
#pragma unroll
  for (int i = 0; i < 4; i++)
    tile[ty + 8 * i][tx] = v[(size_t)(s0 + ty + 8 * i) * 4096 + hd * 128 + d0 + tx];
  __syncthreads();
#pragma unroll
  for (int i = 0; i < 4; i++) {
    int d = ty + 8 * i;
    vt[((size_t)hd * 128 + d0 + d) * 2048 + s0 + tx] = tile[tx][d];
  }
}

// ---------- RoPE cos/sin table (double precision): tab[s][j] = {cos,sin} ----------
__global__ __launch_bounds__(256) void rope_table_kernel(float* __restrict__ tab) {
  int i = blockIdx.x * 256 + threadIdx.x;  // 2048*64
  int j = i & 63, s = i >> 6;
  double freq = pow(10000.0, -(double)j / 64.0);
  double ang = (double)s * freq;
  tab[i * 2] = (float)cos(ang);
  tab[i * 2 + 1] = (float)sin(ang);
}

// ---------- RoPE split: (hi,lo) bf16 [2048][4096] -> rotated (hi,lo) ----------
__global__ __launch_bounds__(256) void rope_split_kernel(
    const u16* __restrict__ ih, const u16* __restrict__ il,
    const float* __restrict__ tab, u16* __restrict__ oh, u16* __restrict__ ol) {
  int idx = blockIdx.x * 256 + threadIdx.x;  // (s, hd, j)
  int j = idx & 63, hd = (idx >> 6) & 31, s = idx >> 11;
  size_t base = (size_t)s * 4096 + hd * 128;
  float xe = bf2f(ih[base + 2 * j]) + bf2f(il[base + 2 * j]);
  float xo = bf2f(ih[base + 2 * j + 1]) + bf2f(il[base + 2 * j + 1]);
  float cs = tab[(s * 64 + j) * 2], sn = tab[(s * 64 + j) * 2 + 1];
  float r0 = xe * cs - xo * sn;
  float r1 = xe * sn + xo * cs;
  u16 h0 = f2bf(r0), h1 = f2bf(r1);
  oh[base + j] = h0;      ol[base + j] = f2bf(r0 - bf2f(h0));
  oh[base + 64 + j] = h1; ol[base + 64 + j] = f2bf(r1 - bf2f(h1));
}

// ---------- GEMM (plain bf16): A [M][K] @ Bt [N][K] -> C [M][N] ----------
template <bool OBF16>
__global__ __launch_bounds__(256) void gemm_kernel(
    const u16* __restrict__ A, const u16* __restrict__ Bt, void* __restrict__ C,
    int M, int N, int K) {
  __shared__ __attribute__((aligned(16))) u16 Al[128 * 32];
  __shared__ __attribute__((aligned(16))) u16 Bl[128 * 32];
  int t = threadIdx.x, l = t & 63, w = t >> 6;
  int m0 = blockIdx.y * 128, n0 = blockIdx.x * 128;
  int wm = (w >> 1) * 64, wn = (w & 1) * 64;
  f32x4 acc[4][4] = {};
  int nk = K >> 5;
  for (int kt = 0; kt < nk; ++kt) {
    int k0 = kt << 5;
#pragma unroll
    for (int i = 0; i < 2; i++) {
      int ci = i * 256 + t;
      int row = ci >> 2, c8 = (ci & 3) * 8;
      gl_lds16(&A[(size_t)(m0 + row) * K + k0 + c8], &Al[ci * 8]);
      gl_lds16(&Bt[(size_t)(n0 + row) * K + k0 + c8], &Bl[ci * 8]);
    }
    __syncthreads();
    short8 af[4], bfr[4];
#pragma unroll
    for (int m = 0; m < 4; m++)
      af[m] = *(const short8*)&Al[(wm + m * 16 + (l & 15)) * 32 + (l >> 4) * 8];
#pragma unroll
    for (int n = 0; n < 4; n++)
      bfr[n] = *(const short8*)&Bl[(wn + n * 16 + (l & 15)) * 32 + (l >> 4) * 8];
#pragma unroll
    for (int m = 0; m < 4; m++)
#pragma unroll
      for (int n = 0; n < 4; n++)
        acc[m][n] = __builtin_amdgcn_mfma_f32_16x16x32_bf16(af[m], bfr[n], acc[m][n], 0, 0, 0);
    __syncthreads();
  }
#pragma unroll
  for (int m = 0; m < 4; m++) {
#pragma unroll
    for (int i = 0; i < 4; i++) {
      int row = m0 + wm + m * 16 + (l >> 4) * 4 + i;
      size_t rb = (size_t)row * N + n0 + wn + (l & 15);
      if (OBF16) {
        u16* Cb = (u16*)C;
#pragma unroll
        for (int n = 0; n < 4; n++) Cb[rb + n * 16] = f2bf(acc[m][n][i]);
      } else {
        float* Cf = (float*)C;
#pragma unroll
        for (int n = 0; n < 4; n++) Cf[rb + n * 16] = acc[m][n][i];
      }
    }
  }
}

// ---------- split GEMM: (Ah+Al) @ (Bh+Bl)^T with 3 products, split bf16 out ----------
__global__ __launch_bounds__(256) void gemm3_kernel(
    const u16* __restrict__ Ah, const u16* __restrict__ Alo,
    const u16* __restrict__ Bh, const u16* __restrict__ Blo,
    u16* __restrict__ Chi, u16* __restrict__ Clo, int M, int N, int K) {
  __shared__ __attribute__((aligned(16))) u16 AH[128 * 32];
  __shared__ __attribute__((aligned(16))) u16 AL[128 * 32];
  __shared__ __attribute__((aligned(16))) u16 BH[128 * 32];
  __shared__ __attribute__((aligned(16))) u16 BL[128 * 32];
  int t = threadIdx.x, l = t & 63, w = t >> 6;
  int m0 = blockIdx.y * 128, n0 = blockIdx.x * 128;
  int wm = (w >> 1) * 64, wn = (w & 1) * 64;
  f32x4 acc[4][4] = {};
  int nk = K >> 5;
  for (int kt = 0; kt < nk; ++kt) {
    int k0 = kt << 5;
#pragma unroll
    for (int i = 0; i < 2; i++) {
      int ci = i * 256 + t;
      int row = ci >> 2, c8 = (ci & 3) * 8;
      size_t ga = (size_t)(m0 + row) * K + k0 + c8;
      size_t gb = (size_t)(n0 + row) * K + k0 + c8;
      gl_lds16(&Ah[ga], &AH[ci * 8]);
      gl_lds16(&Alo[ga], &AL[ci * 8]);
      gl_lds16(&Bh[gb], &BH[ci * 8]);
      gl_lds16(&Blo[gb], &BL[ci * 8]);
    }
    __syncthreads();
    short8 afh[4], afl[4], bfh[4], bfl[4];
#pragma unroll
    for (int m = 0; m < 4; m++) {
      int off = (wm + m * 16 + (l & 15)) * 32 + (l >> 4) * 8;
      afh[m] = *(const short8*)&AH[off];
      afl[m] = *(const short8*)&AL[off];
    }
#pragma unroll
    for (int n = 0; n < 4; n++) {
      int off = (wn + n * 16 + (l & 15)) * 32 + (l >> 4) * 8;
      bfh[n] = *(const short8*)&BH[off];
      bfl[n] = *(const short8*)&BL[off];
    }
#pragma unroll
    for (int m = 0; m < 4; m++)
#pragma unroll
      for (int n = 0; n < 4; n++) {
        acc[m][n] = __builtin_amdgcn_mfma_f32_16x16x32_bf16(afh[m], bfh[n], acc[m][n], 0, 0, 0);
        acc[m][n] = __builtin_amdgcn_mfma_f32_16x16x32_bf16(afh[m], bfl[n], acc[m][n], 0, 0, 0);
        acc[m][n] = __builtin_amdgcn_mfma_f32_16x16x32_bf16(afl[m], bfh[n], acc[m][n], 0, 0, 0);
      }
    __syncthreads();
  }
#pragma unroll
  for (int m = 0; m < 4; m++) {
#pragma unroll
    for (int i = 0; i < 4; i++) {
      int row = m0 + wm + m * 16 + (l >> 4) * 4 + i;
      size_t rb = (size_t)row * N + n0 + wn + (l & 15);
#pragma unroll
      for (int n = 0; n < 4; n++) {
        float f = acc[m][n][i];
        u16 hi = f2bf(f);
        Chi[rb + n * 16] = hi;
        Clo[rb + n * 16] = f2bf(f - bf2f(hi));
      }
    }
  }
}

// ---------- flash attention (no scale, no mask), split-precision QK^T ----------
// q,k as (hi,lo) bf16 [2048][4096]; vt bf16 [32][128][2048]; out bf16 [2048][4096]
__global__ __launch_bounds__(256) void attn_kernel(
    const u16* __restrict__ qh, const u16* __restrict__ ql,
    const u16* __restrict__ kh, const u16* __restrict__ kl,
    const u16* __restrict__ vt, u16* __restrict__ out) {
  __shared__ __attribute__((aligned(16))) u16 KH[64 * 128];   // [kv][d], XOR-swizzled
  __shared__ __attribute__((aligned(16))) u16 KL[64 * 128];
  __shared__ __attribute__((aligned(16))) u16 Vl[128 * 64];   // [d][kv], XOR-swizzled
  __shared__ __attribute__((aligned(16))) u16 Pl[4][16 * 72]; // per-wave [q][kv], pad 72
  int t = threadIdx.x, l = t & 63, w = t >> 6;
  int hd = blockIdx.y, q0 = blockIdx.x * 64;
  int qrow = q0 + w * 16 + (l & 15);
  size_t qoff = (size_t)qrow * 4096 + hd * 128 + (l >> 4) * 8;
  short8 qfh[4], qfl[4];
#pragma unroll
  for (int kc = 0; kc < 4; kc++) {
    qfh[kc] = *(const short8*)&qh[qoff + kc * 32];
    qfl[kc] = *(const short8*)&ql[qoff + kc * 32];
  }
  f32x4 accO[8] = {};
  float mrun = -__builtin_inff(), lrun = 0.f;
  for (int kv0 = 0; kv0 < 2048; kv0 += 64) {
    // stage K hi/lo tiles [64][128]: 16 chunks/row; swizzled source
#pragma unroll
    for (int i = 0; i < 4; i++) {
      int ci = i * 256 + t;
      int row = ci >> 4;
      int cb = (ci & 15) ^ (row & 7);
      size_t src = (size_t)(kv0 + row) * 4096 + hd * 128 + cb * 8;
      gl_lds16(&kh[src], &KH[ci * 8]);
      gl_lds16(&kl[src], &KL[ci * 8]);
    }
    // stage V^T tile [128][64]: 8 chunks/row; swizzled source
#pragma unroll
    for (int i = 0; i < 4; i++) {
      int ci = i * 256 + t;
      int row = ci >> 3;
      int cb = (ci & 7) ^ (row & 7);
      gl_lds16(&vt[((size_t)hd * 128 + row) * 2048 + kv0 + cb * 8], &Vl[ci * 8]);
    }
    __syncthreads();
    // S^T = K @ Q^T with 3-product split
    f32x4 accS[4];
#pragma unroll
    for (int mm = 0; mm < 4; mm++) {
      accS[mm] = (f32x4){0.f, 0.f, 0.f, 0.f};
#pragma unroll
      for (int kc = 0; kc < 4; kc++) {
        int rowk = mm * 16 + (l & 15);
        int logb = rowk * 256 + kc * 64 + (l >> 4) * 16;
        int phys = logb ^ ((rowk & 7) << 4);
        short8 a_h = *(const short8*)((const char*)KH + phys);
        short8 a_l = *(const short8*)((const char*)KL + phys);
        accS[mm] = __builtin_amdgcn_mfma_f32_16x16x32_bf16(a_h, qfh[kc], accS[mm], 0, 0, 0);
        accS[mm] = __builtin_amdgcn_mfma_f32_16x16x32_bf16(a_h, qfl[kc], accS[mm], 0, 0, 0);
        accS[mm] = __builtin_amdgcn_mfma_f32_16x16x32_bf16(a_l, qfh[kc], accS[mm], 0, 0, 0);
      }
    }
    // online softmax; lane owns q-row l&15, kv spread over {l^16,l^32} group
    float tmax = -__builtin_inff();
#pragma unroll
    for (int mm = 0; mm < 4; mm++)
      tmax = fmaxf(tmax, fmaxf(fmaxf(accS[mm][0], accS[mm][1]), fmaxf(accS[mm][2], accS[mm][3])));
    tmax = fmaxf(tmax, __shfl_xor(tmax, 16));
    tmax = fmaxf(tmax, __shfl_xor(tmax, 32));
    float mnew = fmaxf(mrun, tmax);
    float scale = expf(mrun - mnew);
    float psum = 0.f;
#pragma unroll
    for (int mm = 0; mm < 4; mm++) {
      float p0 = expf(accS[mm][0] - mnew), p1 = expf(accS[mm][1] - mnew);
      float p2 = expf(accS[mm][2] - mnew), p3 = expf(accS[mm][3] - mnew);
      psum += (p0 + p1) + (p2 + p3);
      ushort4 pk;
      pk.x = f2bf(p0); pk.y = f2bf(p1); pk.z = f2bf(p2); pk.w = f2bf(p3);
      *(ushort4*)&Pl[w][(l & 15) * 72 + mm * 16 + (l >> 4) * 4] = pk;
    }
    psum += __shfl_xor(psum, 16);
    psum += __shfl_xor(psum, 32);
    lrun = lrun * scale + psum;
    mrun = mnew;
#pragma unroll
    for (int mm = 0; mm < 8; mm++) accO[mm] = accO[mm] * scale;
    // O^T += V^T @ P^T
#pragma unroll
    for (int kc2 = 0; kc2 < 2; kc2++) {
      short8 bp = *(const short8*)((const char*)&Pl[w][0] + (l & 15) * 144 + kc2 * 64 + (l >> 4) * 16);
#pragma unroll
      for (int mm = 0; mm < 8; mm++) {
        int rowd = mm * 16 + (l & 15);
        int logb = rowd * 128 + kc2 * 64 + (l >> 4) * 16;
        int phys = logb ^ ((rowd & 7) << 4);
        short8 av = *(const short8*)((const char*)Vl + phys);
        accO[mm] = __builtin_amdgcn_mfma_f32_16x16x32_bf16(av, bp, accO[mm], 0, 0, 0);
      }
    }
    __syncthreads();
  }
  float rinv = 1.f / lrun;
#pragma unroll
  for (int mm = 0; mm < 8; mm++) {
    ushort4 pk;
    pk.x = f2bf(accO[mm][0] * rinv); pk.y = f2bf(accO[mm][1] * rinv);
    pk.z = f2bf(accO[mm][2] * rinv); pk.w = f2bf(accO[mm][3] * rinv);
    *(ushort4*)&out[(size_t)qrow * 4096 + hd * 128 + mm * 16 + (l >> 4) * 4] = pk;
  }
}

// ---------- silu-mul: x1 *= silu(x3) (bf16, in-place into x1) ----------
__global__ __launch_bounds__(256) void silumul_kernel(u16* __restrict__ x1, const u16* __restrict__ x3) {
  size_t i = ((size_t)blockIdx.x * 256 + threadIdx.x) * 8;
  uint4 a = *(const uint4*)&x1[i];
  uint4 b = *(const uint4*)&x3[i];
  unsigned int* ap = (unsigned int*)&a;
  const unsigned int* bp = (const unsigned int*)&b;
#pragma unroll
  for (int j = 0; j < 4; j++) {
    float a0 = bf2f(ap[j] & 0xffff), a1 = bf2f(ap[j] >> 16);
    float b0 = bf2f(bp[j] & 0xffff), b1 = bf2f(bp[j] >> 16);
    float r0 = a0 * (b0 / (1.f + expf(-b0)));
    float r1 = a1 * (b1 / (1.f + expf(-b1)));
    ap[j] = (unsigned int)f2bf(r0) | ((unsigned int)f2bf(r1) << 16);
  }
  *(uint4*)&x1[i] = a;
}

// ---------- launch ----------
extern "C" void kernel_launch(void* const* d_in, const int* in_sizes, int n_in,
                              void* d_out, int out_size, void* d_ws, size_t ws_size,
                              hipStream_t stream) {
  const float* x      = (const float*)d_in[0];
  const float* wq     = (const float*)d_in[1];
  const float* wk     = (const float*)d_in[2];
  const float* wv     = (const float*)d_in[3];
  const float* wo     = (const float*)d_in[4];
  const float* w1     = (const float*)d_in[5];
  const float* w2     = (const float*)d_in[6];
  const float* w3     = (const float*)d_in[7];
  const float* g_attn = (const float*)d_in[8];
  const float* g_ffn  = (const float*)d_in[9];

  char* ws = (char*)d_ws;
  size_t o = 0;
  auto take = [&](size_t bytes) { char* p = ws + o; o += bytes; return p; };
  const size_t SZ_W   = (size_t)11008 * 4096 * 2;  // rotating weight-hi (max size)
  const size_t SZ_WLO = (size_t)4096 * 4096 * 2;   // weight-lo for wq/wk
  const size_t U      = (size_t)2048 * 4096 * 2;
  const size_t SZ_FF  = (size_t)2048 * 11008 * 2;
  u16* wA      = (u16*)take(SZ_W);
  u16* wB      = (u16*)take(SZ_WLO);
  u16* h_hi    = (u16*)take(U);
  u16* h_lo    = (u16*)take(U);
  u16* qpre_hi = (u16*)take(U);
  u16* qpre_lo = (u16*)take(U);
  u16* kpre_hi = (u16*)take(U);
  u16* kpre_lo = (u16*)take(U);
  u16* v       = (u16*)take(U);
  u16* qb_hi   = (u16*)take(U);
  u16* qb_lo   = (u16*)take(U);
  u16* kb_hi   = (u16*)take(U);
  u16* kb_lo   = (u16*)take(U);
  u16* x3      = (u16*)take(SZ_FF);
  float* tab   = (float*)take((size_t)2048 * 64 * 2 * 4);
  // aliases (non-overlapping lifetimes):
  u16*   vT = qpre_hi;         // dead after rope
  u16*   ao = qpre_lo;         // dead after rope
  float* xo = (float*)kpre_hi; // spans kpre_hi+kpre_lo (2U = 33.5MB), dead after rope
  u16*   h2 = v;               // v dead after vtrans
  u16*   x1 = qb_hi;           // spans qb_hi,qb_lo,part of kb_hi; all dead after attn
  (void)ws_size; (void)in_sizes; (void)n_in; (void)out_size;

  dim3 tb(32, 8);
  dim3 g44(4096 / 32, 4096 / 32);

  rope_table_kernel<<<512, 256, 0, stream>>>(tab);
  // h = rmsnorm(x, g_attn), split
  rmsnorm_kernel<true><<<2048, 256, 0, stream>>>(x, g_attn, h_hi, h_lo);
  // Q = h @ wq (split precision), K likewise
  tconv_split_kernel<<<g44, tb, 0, stream>>>(wq, wA, wB, 4096, 4096);
  gemm3_kernel<<<dim3(32, 16), 256, 0, stream>>>(h_hi, h_lo, wA, wB, qpre_hi, qpre_lo, 2048, 4096, 4096);
  tconv_split_kernel<<<g44, tb, 0, stream>>>(wk, wA, wB, 4096, 4096);
  gemm3_kernel<<<dim3(32, 16), 256, 0, stream>>>(h_hi, h_lo, wA, wB, kpre_hi, kpre_lo, 2048, 4096, 4096);
  // V = h @ wv (plain)
  tconv_kernel<<<g44, tb, 0, stream>>>(wv, wA, 4096, 4096);
  gemm_kernel<true><<<dim3(32, 16), 256, 0, stream>>>(h_hi, wA, v, 2048, 4096, 4096);
  // rope (split in/out, table-driven)
  rope_split_kernel<<<16384, 256, 0, stream>>>(qpre_hi, qpre_lo, tab, qb_hi, qb_lo);
  rope_split_kernel<<<16384, 256, 0, stream>>>(kpre_hi, kpre_lo, tab, kb_hi, kb_lo);
  // v transpose to [h][d][s]
  vtrans_kernel<<<dim3(64, 4, 32), tb, 0, stream>>>(v, vT);
  // attention
  attn_kernel<<<dim3(32, 32), 256, 0, stream>>>(qb_hi, qb_lo, kb_hi, kb_lo, vT, ao);
  // xo = ao @ wo (f32)
  tconv_kernel<<<g44, tb, 0, stream>>>(wo, wA, 4096, 4096);
  gemm_kernel<false><<<dim3(32, 16), 256, 0, stream>>>(ao, wA, xo, 2048, 4096, 4096);
  // h2 = rmsnorm(xo, g_ffn)
  rmsnorm_kernel<false><<<2048, 256, 0, stream>>>(xo, g_ffn, h2, nullptr);
  // FFN
  tconv_kernel<<<dim3(344, 128), tb, 0, stream>>>(w1, wA, 4096, 11008);
  gemm_kernel<true><<<dim3(86, 16), 256, 0, stream>>>(h2, wA, x1, 2048, 11008, 4096);
  tconv_kernel<<<dim3(344, 128), tb, 0, stream>>>(w3, wA, 4096, 11008);
  gemm_kernel<true><<<dim3(86, 16), 256, 0, stream>>>(h2, wA, x3, 2048, 11008, 4096);
  silumul_kernel<<<11008, 256, 0, stream>>>(x1, x3);
  tconv_kernel<<<dim3(128, 344), tb, 0, stream>>>(w2, wA, 11008, 4096);
  gemm_kernel<false><<<dim3(32, 16), 256, 0, stream>>>(x1, wA, (float*)d_out, 2048, 4096, 11008);
}

// Round 3
// 1998.115 us; speedup vs baseline: 1.0382x; 1.0382x over previous
//
#include <hip/hip_runtime.h>
#include <math.h>

// ---------- types / helpers ----------
typedef unsigned short u16;
typedef short short8 __attribute__((ext_vector_type(8)));
typedef float f32x4 __attribute__((ext_vector_type(4)));

#define DEV static __device__ __forceinline__

DEV float bf2f(u16 h) { union { unsigned int u; float f; } v; v.u = ((unsigned int)h) << 16; return v.f; }
DEV u16 f2bf(float f) {
  union { float f; unsigned int u; } v; v.f = f;
  unsigned int r = v.u + 0x7FFFu + ((v.u >> 16) & 1u);  // RNE
  return (u16)(r >> 16);
}

DEV void gl_lds16(const void* g, void* l) {
  __builtin_amdgcn_global_load_lds(
      (const __attribute__((address_space(1))) unsigned int*)g,
      (__attribute__((address_space(3))) unsigned int*)l, 16, 0, 0);
}

template <int N> DEV void vm_wait() {
  if constexpr (N == 0) asm volatile("s_waitcnt vmcnt(0)" ::: "memory");
  else if constexpr (N == 6) asm volatile("s_waitcnt vmcnt(6)" ::: "memory");
  else if constexpr (N == 8) asm volatile("s_waitcnt vmcnt(8)" ::: "memory");
  else static_assert(N == 0 || N == 6 || N == 8, "add literal");
}

// ---------- RMSNorm: f32 [2048][4096] -> bf16 (optionally split hi/lo) ----------
template <bool SPLIT>
__global__ __launch_bounds__(256) void rmsnorm_kernel(
    const float* __restrict__ x, const float* __restrict__ g,
    u16* __restrict__ oh, u16* __restrict__ ol) {
  int row = blockIdx.x, t = threadIdx.x;
  const float* xr = x + (size_t)row * 4096;
  float4 vals[4];
  float s = 0.f;
#pragma unroll
  for (int i = 0; i < 4; i++) {
    vals[i] = ((const float4*)xr)[t + i * 256];
    s += vals[i].x * vals[i].x + vals[i].y * vals[i].y + vals[i].z * vals[i].z + vals[i].w * vals[i].w;
  }
#pragma unroll
  for (int m = 1; m < 64; m <<= 1) s += __shfl_xor(s, m);
  __shared__ float red[4];
  if ((t & 63) == 0) red[t >> 6] = s;
  __syncthreads();
  s = red[0] + red[1] + red[2] + red[3];
  float rinv = rsqrtf(s * (1.f / 4096.f) + 1.1920929e-07f);
#pragma unroll
  for (int i = 0; i < 4; i++) {
    float4 gv = ((const float4*)g)[t + i * 256];
    float4 v = vals[i];
    float f[4] = {v.x * rinv * gv.x, v.y * rinv * gv.y, v.z * rinv * gv.z, v.w * rinv * gv.w};
    ushort4 rh, rl;
    u16* hp = (u16*)&rh; u16* lp = (u16*)&rl;
#pragma unroll
    for (int j = 0; j < 4; j++) {
      u16 hi = f2bf(f[j]);
      hp[j] = hi;
      if (SPLIT) lp[j] = f2bf(f[j] - bf2f(hi));
    }
    ((ushort4*)(oh + (size_t)row * 4096))[t + i * 256] = rh;
    if (SPLIT) ((ushort4*)(ol + (size_t)row * 4096))[t + i * 256] = rl;
  }
}

// ---------- transpose-convert: w f32 [K][N] -> wT bf16 [N][K] ----------
__global__ void tconv_kernel(const float* __restrict__ in, u16* __restrict__ out, int K, int N) {
  __shared__ float tile[32][33];
  int k0 = blockIdx.y * 32, n0 = blockIdx.x * 32;
  int tx = threadIdx.x, ty = threadIdx.y;  // (32,8)
#pragma unroll
  for (int i = 0; i < 4; i++)
    tile[ty + 8 * i][tx] = in[(size_t)(k0 + ty + 8 * i) * N + n0 + tx];
  __syncthreads();
#pragma unroll
  for (int i = 0; i < 4; i++) {
    int n = ty + 8 * i;
    out[(size_t)(n0 + n) * K + k0 + tx] = f2bf(tile[tx][n]);
  }
}

// ---------- transpose-convert split: w f32 [K][N] -> hi/lo bf16 [N][K] ----------
__global__ void tconv_split_kernel(const float* __restrict__ in, u16* __restrict__ oh,
                                   u16* __restrict__ ol, int K, int N) {
  __shared__ float tile[32][33];
  int k0 = blockIdx.y * 32, n0 = blockIdx.x * 32;
  int tx = threadIdx.x, ty = threadIdx.y;  // (32,8)
#pragma unroll
  for (int i = 0; i < 4; i++)
    tile[ty + 8 * i][tx] = in[(size_t)(k0 + ty + 8 * i) * N + n0 + tx];
  __syncthreads();
#pragma unroll
  for (int i = 0; i < 4; i++) {
    int n = ty + 8 * i;
    float f = tile[tx][n];
    u16 hi = f2bf(f);
    size_t idx = (size_t)(n0 + n) * K + k0 + tx;
    oh[idx] = hi;
    ol[idx] = f2bf(f - bf2f(hi));
  }
}

// ---------- bf16 transpose v [2048][4096] -> vT [32][128][2048] ----------
__global__ void vtrans_kernel(const u16* __restrict__ v, u16* __restrict__ vt) {
  __shared__ u16 tile[32][33];
  int s0 = blockIdx.x * 32, d0 = blockIdx.y * 32, hd = blockIdx.z;
  int tx = threadIdx.x, ty = threadIdx.y;  // (32,8)
#pragma unroll
  for (int i = 0; i < 4; i++)
    tile[ty + 8 * i][tx] = v[(size_t)(s0 + ty + 8 * i) * 4096 + hd * 128 + d0 + tx];
  __syncthreads();
#pragma unroll
  for (int i = 0; i < 4; i++) {
    int d = ty + 8 * i;
    vt[((size_t)hd * 128 + d0 + d) * 2048 + s0 + tx] = tile[tx][d];
  }
}

// ---------- RoPE cos/sin table (double precision): tab[s][j] = {cos,sin} ----------
__global__ __launch_bounds__(256) void rope_table_kernel(float* __restrict__ tab) {
  int i = blockIdx.x * 256 + threadIdx.x;  // 2048*64
  int j = i & 63, s = i >> 6;
  double freq = pow(10000.0, -(double)j / 64.0);
  double ang = (double)s * freq;
  tab[i * 2] = (float)cos(ang);
  tab[i * 2 + 1] = (float)sin(ang);
}

// ---------- RoPE split on fused QK buffer [2048][8192] (64 head-slots) ----------
__global__ __launch_bounds__(256) void rope_split_kernel(
    const u16* __restrict__ ih, const u16* __restrict__ il,
    const float* __restrict__ tab, u16* __restrict__ oh, u16* __restrict__ ol) {
  int idx = blockIdx.x * 256 + threadIdx.x;  // (s, head6, j)
  int j = idx & 63, hd = (idx >> 6) & 63, s = idx >> 12;
  size_t base = (size_t)s * 8192 + hd * 128;
  float xe = bf2f(ih[base + 2 * j]) + bf2f(il[base + 2 * j]);
  float xo = bf2f(ih[base + 2 * j + 1]) + bf2f(il[base + 2 * j + 1]);
  float cs = tab[(s * 64 + j) * 2], sn = tab[(s * 64 + j) * 2 + 1];
  float r0 = xe * cs - xo * sn;
  float r1 = xe * sn + xo * cs;
  u16 h0 = f2bf(r0), h1 = f2bf(r1);
  oh[base + j] = h0;      ol[base + j] = f2bf(r0 - bf2f(h0));
  oh[base + 64 + j] = h1; ol[base + 64 + j] = f2bf(r1 - bf2f(h1));
}

// ---------- pipelined GEMM: A bf16 [M][lda] @ Bt bf16 [N][K] -> C [M][N] ----------
// BM=256, BK=64, 512 thr (8 waves, 2M x 4N). Double-buffered LDS, counted vmcnt,
// XOR-swizzled LDS (linear dest + inverse-swizzled source + swizzled read).
template <int BN, bool OBF16>
__global__ __launch_bounds__(512, 2) void gemm_pipe(
    const u16* __restrict__ A, const u16* __restrict__ Bt, void* __restrict__ C,
    int M, int N, int K, int lda) {
  constexpr int NW = BN / 64;       // B frags per wave (4 or 2)
  constexpr int LPT = 4 + BN / 64;  // loads/thread/tile: A 4 + B (4 or 2)
  __shared__ __attribute__((aligned(16))) u16 Asb[2][256 * 64];
  __shared__ __attribute__((aligned(16))) u16 Bsb[2][BN * 64];
  int t = threadIdx.x, l = t & 63, w = t >> 6;
  int m0 = blockIdx.y * 256, n0 = blockIdx.x * BN;
  int wm = (w >> 2) * 128, wn = (w & 3) * (BN / 4);
  f32x4 acc[8][NW] = {};
  int nk = K >> 6;

  auto stage = [&](int tt, int bb) {
    int k0 = tt << 6;
#pragma unroll
    for (int i = 0; i < 4; i++) {
      int id = i * 512 + t;
      int r = id >> 3, cb = id & 7;
      int csw = ((cb * 16) ^ ((r & 7) << 4)) >> 1;
      gl_lds16(&A[(size_t)(m0 + r) * lda + k0 + csw], &Asb[bb][id * 8]);
    }
#pragma unroll
    for (int i = 0; i < BN / 64; i++) {
      int id = i * 512 + t;
      int r = id >> 3, cb = id & 7;
      int csw = ((cb * 16) ^ ((r & 7) << 4)) >> 1;
      gl_lds16(&Bt[(size_t)(n0 + r) * K + k0 + csw], &Bsb[bb][id * 8]);
    }
  };

  stage(0, 0);
  for (int kt = 0; kt < nk; ++kt) {
    int cur = kt & 1;
    __builtin_amdgcn_sched_barrier(0);
    __builtin_amdgcn_s_barrier();
    if (kt + 1 < nk) { stage(kt + 1, cur ^ 1); vm_wait<LPT>(); }
    else vm_wait<0>();
#pragma unroll
    for (int kh = 0; kh < 2; kh++) {
      short8 af[8], bf[NW];
#pragma unroll
      for (int m = 0; m < 8; m++) {
        int row = wm + m * 16 + (l & 15);
        int pb = (row * 128 + kh * 64 + (l >> 4) * 16) ^ ((row & 7) << 4);
        af[m] = *(const short8*)((const char*)Asb[cur] + pb);
      }
#pragma unroll
      for (int n = 0; n < NW; n++) {
        int row = wn + n * 16 + (l & 15);
        int pb = (row * 128 + kh * 64 + (l >> 4) * 16) ^ ((row & 7) << 4);
        bf[n] = *(const short8*)((const char*)Bsb[cur] + pb);
      }
      __builtin_amdgcn_s_setprio(1);
#pragma unroll
      for (int m = 0; m < 8; m++)
#pragma unroll
        for (int n = 0; n < NW; n++)
          acc[m][n] = __builtin_amdgcn_mfma_f32_16x16x32_bf16(af[m], bf[n], acc[m][n], 0, 0, 0);
      __builtin_amdgcn_s_setprio(0);
    }
  }
#pragma unroll
  for (int m = 0; m < 8; m++) {
#pragma unroll
    for (int i = 0; i < 4; i++) {
      int row = m0 + wm + m * 16 + (l >> 4) * 4 + i;
      size_t rb = (size_t)row * N + n0 + wn + (l & 15);
      if (OBF16) {
        u16* Cb = (u16*)C;
#pragma unroll
        for (int n = 0; n < NW; n++) Cb[rb + n * 16] = f2bf(acc[m][n][i]);
      } else {
        float* Cf = (float*)C;
#pragma unroll
        for (int n = 0; n < NW; n++) Cf[rb + n * 16] = acc[m][n][i];
      }
    }
  }
}

// ---------- pipelined split GEMM: (Ah+Al) @ (Bh+Bl)^T, 3 products, split out ----------
// BM=BN=128, BK=64, 512 thr (8 waves, 2M x 4N; per-wave 64x32 out).
__global__ __launch_bounds__(512, 2) void gemm3_pipe(
    const u16* __restrict__ Ah, const u16* __restrict__ Alo,
    const u16* __restrict__ Bh, const u16* __restrict__ Blo,
    u16* __restrict__ Chi, u16* __restrict__ Clo, int M, int N, int K) {
  __shared__ __attribute__((aligned(16))) u16 AH[2][128 * 64];
  __shared__ __attribute__((aligned(16))) u16 AL[2][128 * 64];
  __shared__ __attribute__((aligned(16))) u16 BH[2][128 * 64];
  __shared__ __attribute__((aligned(16))) u16 BL[2][128 * 64];
  int t = threadIdx.x, l = t & 63, w = t >> 6;
  int m0 = blockIdx.y * 128, n0 = blockIdx.x * 128;
  int wm = (w >> 2) * 64, wn = (w & 3) * 32;
  f32x4 acc[4][2] = {};
  int nk = K >> 6;

  auto stage = [&](int tt, int bb) {
    int k0 = tt << 6;
#pragma unroll
    for (int i = 0; i < 2; i++) {
      int id = i * 512 + t;
      int r = id >> 3, cb = id & 7;
      int csw = ((cb * 16) ^ ((r & 7) << 4)) >> 1;
      size_t ga = (size_t)(m0 + r) * K + k0 + csw;
      size_t gb = (size_t)(n0 + r) * K + k0 + csw;
      gl_lds16(&Ah[ga], &AH[bb][id * 8]);
      gl_lds16(&Alo[ga], &AL[bb][id * 8]);
      gl_lds16(&Bh[gb], &BH[bb][id * 8]);
      gl_lds16(&Blo[gb], &BL[bb][id * 8]);
    }
  };

  stage(0, 0);
  for (int kt = 0; kt < nk; ++kt) {
    int cur = kt & 1;
    __builtin_amdgcn_sched_barrier(0);
    __builtin_amdgcn_s_barrier();
    if (kt + 1 < nk) { stage(kt + 1, cur ^ 1); vm_wait<8>(); }
    else vm_wait<0>();
#pragma unroll
    for (int kh = 0; kh < 2; kh++) {
      short8 afh[4], afl[4], bfh[2], bfl[2];
#pragma unroll
      for (int m = 0; m < 4; m++) {
        int row = wm + m * 16 + (l & 15);
        int pb = (row * 128 + kh * 64 + (l >> 4) * 16) ^ ((row & 7) << 4);
        afh[m] = *(const short8*)((const char*)AH[cur] + pb);
        afl[m] = *(const short8*)((const char*)AL[cur] + pb);
      }
#pragma unroll
      for (int n = 0; n < 2; n++) {
        int row = wn + n * 16 + (l & 15);
        int pb = (row * 128 + kh * 64 + (l >> 4) * 16) ^ ((row & 7) << 4);
        bfh[n] = *(const short8*)((const char*)BH[cur] + pb);
        bfl[n] = *(const short8*)((const char*)BL[cur] + pb);
      }
      __builtin_amdgcn_s_setprio(1);
#pragma unroll
      for (int m = 0; m < 4; m++)
#pragma unroll
        for (int n = 0; n < 2; n++) {
          acc[m][n] = __builtin_amdgcn_mfma_f32_16x16x32_bf16(afh[m], bfh[n], acc[m][n], 0, 0, 0);
          acc[m][n] = __builtin_amdgcn_mfma_f32_16x16x32_bf16(afh[m], bfl[n], acc[m][n], 0, 0, 0);
          acc[m][n] = __builtin_amdgcn_mfma_f32_16x16x32_bf16(afl[m], bfh[n], acc[m][n], 0, 0, 0);
        }
      __builtin_amdgcn_s_setprio(0);
    }
  }
#pragma unroll
  for (int m = 0; m < 4; m++) {
#pragma unroll
    for (int i = 0; i < 4; i++) {
      int row = m0 + wm + m * 16 + (l >> 4) * 4 + i;
      size_t rb = (size_t)row * N + n0 + wn + (l & 15);
#pragma unroll
      for (int n = 0; n < 2; n++) {
        float f = acc[m][n][i];
        u16 hi = f2bf(f);
        Chi[rb + n * 16] = hi;
        Clo[rb + n * 16] = f2bf(f - bf2f(hi));
      }
    }
  }
}

// ---------- flash attention (no scale, no mask), split-precision QK^T ----------
// q,k as (hi,lo) bf16 rows of stride 8192; vt bf16 [32][128][2048]; out bf16 [2048][4096]
__global__ __launch_bounds__(256) void attn_kernel(
    const u16* __restrict__ qh, const u16* __restrict__ ql,
    const u16* __restrict__ kh, const u16* __restrict__ kl,
    const u16* __restrict__ vt, u16* __restrict__ out) {
  const int QS = 8192;
  __shared__ __attribute__((aligned(16))) u16 KH[64 * 128];   // [kv][d], XOR-swizzled
  __shared__ __attribute__((aligned(16))) u16 KL[64 * 128];
  __shared__ __attribute__((aligned(16))) u16 Vl[128 * 64];   // [d][kv], XOR-swizzled
  __shared__ __attribute__((aligned(16))) u16 Pl[4][16 * 72]; // per-wave [q][kv], pad 72
  int t = threadIdx.x, l = t & 63, w = t >> 6;
  int hd = blockIdx.y, q0 = blockIdx.x * 64;
  int qrow = q0 + w * 16 + (l & 15);
  size_t qoff = (size_t)qrow * QS + hd * 128 + (l >> 4) * 8;
  short8 qfh[4], qfl[4];
#pragma unroll
  for (int kc = 0; kc < 4; kc++) {
    qfh[kc] = *(const short8*)&qh[qoff + kc * 32];
    qfl[kc] = *(const short8*)&ql[qoff + kc * 32];
  }
  f32x4 accO[8] = {};
  float mrun = -__builtin_inff(), lrun = 0.f;
  for (int kv0 = 0; kv0 < 2048; kv0 += 64) {
    // stage K hi/lo tiles [64][128]: 16 chunks/row; swizzled source
#pragma unroll
    for (int i = 0; i < 4; i++) {
      int ci = i * 256 + t;
      int row = ci >> 4;
      int cb = (ci & 15) ^ (row & 7);
      size_t src = (size_t)(kv0 + row) * QS + hd * 128 + cb * 8;
      gl_lds16(&kh[src], &KH[ci * 8]);
      gl_lds16(&kl[src], &KL[ci * 8]);
    }
    // stage V^T tile [128][64]: 8 chunks/row; swizzled source
#pragma unroll
    for (int i = 0; i < 4; i++) {
      int ci = i * 256 + t;
      int row = ci >> 3;
      int cb = (ci & 7) ^ (row & 7);
      gl_lds16(&vt[((size_t)hd * 128 + row) * 2048 + kv0 + cb * 8], &Vl[ci * 8]);
    }
    __syncthreads();
    // S^T = K @ Q^T with 3-product split
    f32x4 accS[4];
#pragma unroll
    for (int mm = 0; mm < 4; mm++) {
      accS[mm] = (f32x4){0.f, 0.f, 0.f, 0.f};
#pragma unroll
      for (int kc = 0; kc < 4; kc++) {
        int rowk = mm * 16 + (l & 15);
        int logb = rowk * 256 + kc * 64 + (l >> 4) * 16;
        int phys = logb ^ ((rowk & 7) << 4);
        short8 a_h = *(const short8*)((const char*)KH + phys);
        short8 a_l = *(const short8*)((const char*)KL + phys);
        accS[mm] = __builtin_amdgcn_mfma_f32_16x16x32_bf16(a_h, qfh[kc], accS[mm], 0, 0, 0);
        accS[mm] = __builtin_amdgcn_mfma_f32_16x16x32_bf16(a_h, qfl[kc], accS[mm], 0, 0, 0);
        accS[mm] = __builtin_amdgcn_mfma_f32_16x16x32_bf16(a_l, qfh[kc], accS[mm], 0, 0, 0);
      }
    }
    // online softmax; lane owns q-row l&15, kv spread over {l^16,l^32} group
    float tmax = -__builtin_inff();
#pragma unroll
    for (int mm = 0; mm < 4; mm++)
      tmax = fmaxf(tmax, fmaxf(fmaxf(accS[mm][0], accS[mm][1]), fmaxf(accS[mm][2], accS[mm][3])));
    tmax = fmaxf(tmax, __shfl_xor(tmax, 16));
    tmax = fmaxf(tmax, __shfl_xor(tmax, 32));
    float mnew = fmaxf(mrun, tmax);
    float scale = expf(mrun - mnew);
    float psum = 0.f;
#pragma unroll
    for (int mm = 0; mm < 4; mm++) {
      float p0 = expf(accS[mm][0] - mnew), p1 = expf(accS[mm][1] - mnew);
      float p2 = expf(accS[mm][2] - mnew), p3 = expf(accS[mm][3] - mnew);
      psum += (p0 + p1) + (p2 + p3);
      ushort4 pk;
      pk.x = f2bf(p0); pk.y = f2bf(p1); pk.z = f2bf(p2); pk.w = f2bf(p3);
      *(ushort4*)&Pl[w][(l & 15) * 72 + mm * 16 + (l >> 4) * 4] = pk;
    }
    psum += __shfl_xor(psum, 16);
    psum += __shfl_xor(psum, 32);
    lrun = lrun * scale + psum;
    mrun = mnew;
#pragma unroll
    for (int mm = 0; mm < 8; mm++) accO[mm] = accO[mm] * scale;
    // O^T += V^T @ P^T
#pragma unroll
    for (int kc2 = 0; kc2 < 2; kc2++) {
      short8 bp = *(const short8*)((const char*)&Pl[w][0] + (l & 15) * 144 + kc2 * 64 + (l >> 4) * 16);
#pragma unroll
      for (int mm = 0; mm < 8; mm++) {
        int rowd = mm * 16 + (l & 15);
        int logb = rowd * 128 + kc2 * 64 + (l >> 4) * 16;
        int phys = logb ^ ((rowd & 7) << 4);
        short8 av = *(const short8*)((const char*)Vl + phys);
        accO[mm] = __builtin_amdgcn_mfma_f32_16x16x32_bf16(av, bp, accO[mm], 0, 0, 0);
      }
    }
    __syncthreads();
  }
  float rinv = 1.f / lrun;
#pragma unroll
  for (int mm = 0; mm < 8; mm++) {
    ushort4 pk;
    pk.x = f2bf(accO[mm][0] * rinv); pk.y = f2bf(accO[mm][1] * rinv);
    pk.z = f2bf(accO[mm][2] * rinv); pk.w = f2bf(accO[mm][3] * rinv);
    *(ushort4*)&out[(size_t)qrow * 4096 + hd * 128 + mm * 16 + (l >> 4) * 4] = pk;
  }
}

// ---------- silu-mul on fused x1x3 [2048][22016]: x1 *= silu(x3) in place ----------
__global__ __launch_bounds__(256) void silumul_kernel(u16* __restrict__ x1x3) {
  int cg = blockIdx.x * 256 + threadIdx.x;  // column-group (8 elems)
  if (cg >= 1376) return;
  size_t base = (size_t)blockIdx.y * 22016 + cg * 8;
  uint4 a = *(const uint4*)&x1x3[base];
  uint4 b = *(const uint4*)&x1x3[base + 11008];
  unsigned int* ap = (unsigned int*)&a;
  const unsigned int* bp = (const unsigned int*)&b;
#pragma unroll
  for (int j = 0; j < 4; j++) {
    float a0 = bf2f(ap[j] & 0xffff), a1 = bf2f(ap[j] >> 16);
    float b0 = bf2f(bp[j] & 0xffff), b1 = bf2f(bp[j] >> 16);
    float r0 = a0 * (b0 / (1.f + expf(-b0)));
    float r1 = a1 * (b1 / (1.f + expf(-b1)));
    ap[j] = (unsigned int)f2bf(r0) | ((unsigned int)f2bf(r1) << 16);
  }
  *(uint4*)&x1x3[base] = a;
}

// ---------- launch ----------
extern "C" void kernel_launch(void* const* d_in, const int* in_sizes, int n_in,
                              void* d_out, int out_size, void* d_ws, size_t ws_size,
                              hipStream_t stream) {
  const float* x      = (const float*)d_in[0];
  const float* wq     = (const float*)d_in[1];
  const float* wk     = (const float*)d_in[2];
  const float* wv     = (const float*)d_in[3];
  const float* wo     = (const float*)d_in[4];
  const float* w1     = (const float*)d_in[5];
  const float* w2     = (const float*)d_in[6];
  const float* w3     = (const float*)d_in[7];
  const float* g_attn = (const float*)d_in[8];
  const float* g_ffn  = (const float*)d_in[9];

  char* ws = (char*)d_ws;
  const size_t MB = 1024 * 1024;
  // region layout (bytes)
  char* R0 = ws;                                  // 180.4MB weights-hi / plain
  char* R1 = R0 + (size_t)22016 * 4096 * 2;       // 67.1MB weights-lo; later xo+h2
  char* R3 = R1 + (size_t)8192 * 4096 * 2;        // 67.1MB qkpre; later v,vT,ao
  char* R4 = R3 + (size_t)8192 * 4096 * 2;        // 67.1MB qkb; later x1x3 (spans into R2)
  char* R2 = R4 + (size_t)8192 * 4096 * 2;        // 33.6MB h_hi,h_lo
  char* RT = R2 + (size_t)4096 * 4096 * 2;        // 1MB rope table
  (void)MB; (void)ws_size; (void)in_sizes; (void)n_in; (void)out_size;

  u16* wA = (u16*)R0;
  u16* wB = (u16*)R1;
  u16* qkpre_hi = (u16*)R3;
  u16* qkpre_lo = (u16*)(R3 + (size_t)2048 * 8192 * 2);
  u16* qkb_hi = (u16*)R4;
  u16* qkb_lo = (u16*)(R4 + (size_t)2048 * 8192 * 2);
  u16* h_hi = (u16*)R2;
  u16* h_lo = (u16*)(R2 + (size_t)2048 * 4096 * 2);
  float* tab = (float*)RT;
  // aliases (disjoint lifetimes)
  u16* v    = (u16*)R3;
  u16* vT   = (u16*)(R3 + (size_t)2048 * 4096 * 2);
  u16* ao   = (u16*)(R3 + (size_t)2048 * 8192 * 2);
  float* xo = (float*)R1;
  u16* h2   = (u16*)(R1 + (size_t)2048 * 4096 * 4);
  u16* x1x3 = (u16*)R4;

  dim3 tb(32, 8);
  dim3 g44(4096 / 32, 4096 / 32);

  rope_table_kernel<<<512, 256, 0, stream>>>(tab);
  rmsnorm_kernel<true><<<2048, 256, 0, stream>>>(x, g_attn, h_hi, h_lo);
  // fused Q|K projection (split precision)
  tconv_split_kernel<<<g44, tb, 0, stream>>>(wq, wA, wB, 4096, 4096);
  tconv_split_kernel<<<g44, tb, 0, stream>>>(wk, wA + (size_t)4096 * 4096, wB + (size_t)4096 * 4096, 4096, 4096);
  gemm3_pipe<<<dim3(64, 16), 512, 0, stream>>>(h_hi, h_lo, wA, wB, qkpre_hi, qkpre_lo, 2048, 8192, 4096);
  rope_split_kernel<<<32768, 256, 0, stream>>>(qkpre_hi, qkpre_lo, tab, qkb_hi, qkb_lo);
  // V projection (plain)
  tconv_kernel<<<g44, tb, 0, stream>>>(wv, wA, 4096, 4096);
  gemm_pipe<128, true><<<dim3(32, 8), 512, 0, stream>>>(h_hi, wA, v, 2048, 4096, 4096, 4096);
  vtrans_kernel<<<dim3(64, 4, 32), tb, 0, stream>>>(v, vT);
  // attention
  attn_kernel<<<dim3(32, 32), 256, 0, stream>>>(qkb_hi, qkb_lo, qkb_hi + 4096, qkb_lo + 4096, vT, ao);
  // xo = ao @ wo (f32)
  tconv_kernel<<<g44, tb, 0, stream>>>(wo, wA, 4096, 4096);
  gemm_pipe<128, false><<<dim3(32, 8), 512, 0, stream>>>(ao, wA, xo, 2048, 4096, 4096, 4096);
  rmsnorm_kernel<false><<<2048, 256, 0, stream>>>(xo, g_ffn, h2, nullptr);
  // fused FFN up: x1|x3 = h2 @ [w1 w3]
  tconv_kernel<<<dim3(344, 128), tb, 0, stream>>>(w1, wA, 4096, 11008);
  tconv_kernel<<<dim3(344, 128), tb, 0, stream>>>(w3, wA + (size_t)11008 * 4096, 4096, 11008);
  gemm_pipe<256, true><<<dim3(86, 8), 512, 0, stream>>>(h2, wA, x1x3, 2048, 22016, 4096, 4096);
  silumul_kernel<<<dim3(6, 2048), 256, 0, stream>>>(x1x3);
  // out = (x1*silu(x3)) @ w2
  tconv_kernel<<<dim3(128, 344), tb, 0, stream>>>(w2, wA, 11008, 4096);
  gemm_pipe<128, false><<<dim3(32, 8), 512, 0, stream>>>(x1x3, wA, (float*)d_out, 2048, 4096, 11008, 22016);
}

// Round 4
// 1921.342 us; speedup vs baseline: 1.0796x; 1.0400x over previous
//
#include <hip/hip_runtime.h>
#include <math.h>

// ---------- types / helpers ----------
typedef unsigned short u16;
typedef short short8 __attribute__((ext_vector_type(8)));
typedef float f32x4 __attribute__((ext_vector_type(4)));

#define DEV static __device__ __forceinline__

DEV float bf2f(u16 h) { union { unsigned int u; float f; } v; v.u = ((unsigned int)h) << 16; return v.f; }
DEV u16 f2bf(float f) {
  union { float f; unsigned int u; } v; v.f = f;
  unsigned int r = v.u + 0x7FFFu + ((v.u >> 16) & 1u);  // RNE
  return (u16)(r >> 16);
}

DEV void gl_lds16(const void* g, void* l) {
  __builtin_amdgcn_global_load_lds(
      (const __attribute__((address_space(1))) unsigned int*)g,
      (__attribute__((address_space(3))) unsigned int*)l, 16, 0, 0);
}

template <int N> DEV void vm_wait() {
  if constexpr (N == 0) asm volatile("s_waitcnt vmcnt(0)" ::: "memory");
  else if constexpr (N == 4) asm volatile("s_waitcnt vmcnt(4)" ::: "memory");
  else if constexpr (N == 6) asm volatile("s_waitcnt vmcnt(6)" ::: "memory");
  else if constexpr (N == 8) asm volatile("s_waitcnt vmcnt(8)" ::: "memory");
  else static_assert(N == 0 || N == 4 || N == 6 || N == 8, "add literal");
}

// ---------- RMSNorm: f32 [2048][4096] -> bf16 (optionally split hi/lo) ----------
template <bool SPLIT>
__global__ __launch_bounds__(256) void rmsnorm_kernel(
    const float* __restrict__ x, const float* __restrict__ g,
    u16* __restrict__ oh, u16* __restrict__ ol) {
  int row = blockIdx.x, t = threadIdx.x;
  const float* xr = x + (size_t)row * 4096;
  float4 vals[4];
  float s = 0.f;
#pragma unroll
  for (int i = 0; i < 4; i++) {
    vals[i] = ((const float4*)xr)[t + i * 256];
    s += vals[i].x * vals[i].x + vals[i].y * vals[i].y + vals[i].z * vals[i].z + vals[i].w * vals[i].w;
  }
#pragma unroll
  for (int m = 1; m < 64; m <<= 1) s += __shfl_xor(s, m);
  __shared__ float red[4];
  if ((t & 63) == 0) red[t >> 6] = s;
  __syncthreads();
  s = red[0] + red[1] + red[2] + red[3];
  float rinv = rsqrtf(s * (1.f / 4096.f) + 1.1920929e-07f);
#pragma unroll
  for (int i = 0; i < 4; i++) {
    float4 gv = ((const float4*)g)[t + i * 256];
    float4 v = vals[i];
    float f[4] = {v.x * rinv * gv.x, v.y * rinv * gv.y, v.z * rinv * gv.z, v.w * rinv * gv.w};
    ushort4 rh, rl;
    u16* hp = (u16*)&rh; u16* lp = (u16*)&rl;
#pragma unroll
    for (int j = 0; j < 4; j++) {
      u16 hi = f2bf(f[j]);
      hp[j] = hi;
      if (SPLIT) lp[j] = f2bf(f[j] - bf2f(hi));
    }
    ((ushort4*)(oh + (size_t)row * 4096))[t + i * 256] = rh;
    if (SPLIT) ((ushort4*)(ol + (size_t)row * 4096))[t + i * 256] = rl;
  }
}

// ---------- transpose-convert: w f32 [K][N] -> wT bf16 [N][K] ----------
__global__ void tconv_kernel(const float* __restrict__ in, u16* __restrict__ out, int K, int N) {
  __shared__ float tile[32][33];
  int k0 = blockIdx.y * 32, n0 = blockIdx.x * 32;
  int tx = threadIdx.x, ty = threadIdx.y;  // (32,8)
#pragma unroll
  for (int i = 0; i < 4; i++)
    tile[ty + 8 * i][tx] = in[(size_t)(k0 + ty + 8 * i) * N + n0 + tx];
  __syncthreads();
#pragma unroll
  for (int i = 0; i < 4; i++) {
    int n = ty + 8 * i;
    out[(size_t)(n0 + n) * K + k0 + tx] = f2bf(tile[tx][n]);
  }
}

// ---------- transpose-convert split: w f32 [K][N] -> hi/lo bf16 [N][K] ----------
__global__ void tconv_split_kernel(const float* __restrict__ in, u16* __restrict__ oh,
                                   u16* __restrict__ ol, int K, int N) {
  __shared__ float tile[32][33];
  int k0 = blockIdx.y * 32, n0 = blockIdx.x * 32;
  int tx = threadIdx.x, ty = threadIdx.y;  // (32,8)
#pragma unroll
  for (int i = 0; i < 4; i++)
    tile[ty + 8 * i][tx] = in[(size_t)(k0 + ty + 8 * i) * N + n0 + tx];
  __syncthreads();
#pragma unroll
  for (int i = 0; i < 4; i++) {
    int n = ty + 8 * i;
    float f = tile[tx][n];
    u16 hi = f2bf(f);
    size_t idx = (size_t)(n0 + n) * K + k0 + tx;
    oh[idx] = hi;
    ol[idx] = f2bf(f - bf2f(hi));
  }
}

// ---------- bf16 transpose v [2048][4096] -> vT [32][128][2048] ----------
__global__ void vtrans_kernel(const u16* __restrict__ v, u16* __restrict__ vt) {
  __shared__ u16 tile[32][33];
  int s0 = blockIdx.x * 32, d0 = blockIdx.y * 32, hd = blockIdx.z;
  int tx = threadIdx.x, ty = threadIdx.y;  // (32,8)
#pragma unroll
  for (int i = 0; i < 4; i++)
    tile[ty + 8 * i][tx] = v[(size_t)(s0 + ty + 8 * i) * 4096 + hd * 128 + d0 + tx];
  __syncthreads();
#pragma unroll
  for (int i = 0; i < 4; i++) {
    int d = ty + 8 * i;
    vt[((size_t)hd * 128 + d0 + d) * 2048 + s0 + tx] = tile[tx][d];
  }
}

// ---------- RoPE cos/sin table (double precision): tab[s][j] = {cos,sin} ----------
__global__ __launch_bounds__(256) void rope_table_kernel(float* __restrict__ tab) {
  int i = blockIdx.x * 256 + threadIdx.x;  // 2048*64
  int j = i & 63, s = i >> 6;
  double freq = pow(10000.0, -(double)j / 64.0);
  double ang = (double)s * freq;
  tab[i * 2] = (float)cos(ang);
  tab[i * 2 + 1] = (float)sin(ang);
}

// ---------- RoPE in place on (hi,lo) [2048][8192]; one wave owns one 128-col slot ----------
__global__ __launch_bounds__(256) void rope_inplace_kernel(
    u16* hi, u16* lo, const float* __restrict__ tab) {
  int idx = blockIdx.x * 256 + threadIdx.x;  // (s, slot6, j)
  int j = idx & 63, hd = (idx >> 6) & 63, s = idx >> 12;
  size_t base = (size_t)s * 8192 + hd * 128;
  float xe = bf2f(hi[base + 2 * j]) + bf2f(lo[base + 2 * j]);
  float xo = bf2f(hi[base + 2 * j + 1]) + bf2f(lo[base + 2 * j + 1]);
  float cs = tab[(s * 64 + j) * 2], sn = tab[(s * 64 + j) * 2 + 1];
  float r0 = xe * cs - xo * sn;
  float r1 = xe * sn + xo * cs;
  u16 h0 = f2bf(r0), h1 = f2bf(r1);
  hi[base + j] = h0;      lo[base + j] = f2bf(r0 - bf2f(h0));
  hi[base + 64 + j] = h1; lo[base + 64 + j] = f2bf(r1 - bf2f(h1));
}

// ---------- 8-phase 256x256 GEMM (T1+T2+T3+T4+T5) ----------
// A bf16 [M][lda] @ Bt bf16 [N][ldb] -> C [M][N]. 512 thr = 8 waves (2M x 4N).
// TRIK: K' = 3*Kseg with per-segment operand select: seg0 A*B, seg1 A2*B, seg2 A*B2
// (split-bf16 product (Ah+Al)(Bh+Bl) ~= AhBh + AlBh + AhBl as one plain GEMM).
// Schedule per K-tile t (buf d=t&1), phases {ds-reads; stage; bar; lgkm0; 16 MFMA; bar}:
//  ph1: read af0-3+bf0-1, stage (t+1).B0   ph2: read bf2-3, stage (t+1).B1
//  ph3: read af4-7                          ph4: stage (t+2).A, vmcnt(4)
// Hazards: (t+1).B -> B[d^1], read-complete at (t-1).ph2.  (t+2).A -> A[d],
// read-complete at t.ph3 (lgkm0+barrier precede ph4's issue).  vmcnt(4) leaves
// exactly (t+2).A's 4 loads in flight; everything older (incl (t+1).B1) landed.
template <int OUT, bool TRIK>  // OUT: 0=f32, 1=bf16, 2=split hi/lo
__global__ __launch_bounds__(512, 2) void gemm8_kernel(
    const u16* __restrict__ A, const u16* __restrict__ A2,
    const u16* __restrict__ B, const u16* __restrict__ B2,
    void* __restrict__ C, u16* __restrict__ C2,
    int M, int N, int K, int lda, int ldb) {
  __shared__ __attribute__((aligned(16))) u16 As[2][2][128 * 64];
  __shared__ __attribute__((aligned(16))) u16 Bs[2][2][128 * 64];
  int t = threadIdx.x, l = t & 63, w = t >> 6;
  // bijective chunked XCD swizzle (grid % 8 == 0 guaranteed by launch)
  int nbx = gridDim.x;
  int nwg = nbx * gridDim.y;
  int lin = blockIdx.y * nbx + blockIdx.x;
  int cpx = nwg >> 3;
  int swz = (lin & 7) * cpx + (lin >> 3);
  int bx = swz % nbx, by = swz / nbx;
  int m0 = by * 256, n0 = bx * 256;
  int wm = w >> 2, wn = w & 3, bh = wn >> 1;
  f32x4 acc[8][4] = {};
  int nk = K >> 6;

  auto stageA = [&](int kt, int dd) {  // both halves, 4 loads/thread
    const u16* Ab = A; int kc = kt << 6;
    if (TRIK) { int seg = kt >> 6; Ab = (seg == 1) ? A2 : A; kc = (kt & 63) << 6; }
#pragma unroll
    for (int i = 0; i < 4; i++) {
      int id = i * 512 + t;
      int hh = id >> 10, idc = id & 1023;
      int r = idc >> 3, cb = idc & 7;
      int csw = ((cb * 16) ^ ((r & 7) << 4)) >> 1;
      gl_lds16(&Ab[(size_t)(m0 + hh * 128 + r) * lda + kc + csw], &As[dd][hh][idc * 8]);
    }
  };
  auto stageB = [&](int kt, int dd, int hh) {  // one half, 2 loads/thread
    const u16* Bb = B; int kc = kt << 6;
    if (TRIK) { int seg = kt >> 6; Bb = (seg == 2) ? B2 : B; kc = (kt & 63) << 6; }
#pragma unroll
    for (int i = 0; i < 2; i++) {
      int id = i * 512 + t;
      int r = id >> 3, cb = id & 7;
      int csw = ((cb * 16) ^ ((r & 7) << 4)) >> 1;
      gl_lds16(&Bb[(size_t)(n0 + hh * 128 + r) * ldb + kc + csw], &Bs[dd][hh][id * 8]);
    }
  };

  // prologue: tile0 fully + tile1's A; drain to tile0-landed
  stageA(0, 0);
  stageB(0, 0, 0);
  stageB(0, 0, 1);
  if (nk > 1) stageA(1, 1);
  vm_wait<4>();
  __builtin_amdgcn_s_barrier();

  short8 af[4][2], bf[4][2];
  int lq = l >> 4, lr = l & 15;
  for (int kt = 0; kt < nk; ++kt) {
    int d = kt & 1;
    const char* Ax = (const char*)As[d][wm];
    const char* Bx = (const char*)Bs[d][bh];
    // ===== phase 1: af0-3 + bf0-1; stage (t+1).B0; MFMA m0-3 x n0-1 =====
#pragma unroll
    for (int m = 0; m < 4; m++) {
      int r = m * 16 + lr;
      int rb = r * 128, rx = (r & 7) << 4;
#pragma unroll
      for (int kh = 0; kh < 2; kh++)
        af[m][kh] = *(const short8*)(Ax + rb + ((kh * 64 + lq * 16) ^ rx));
    }
#pragma unroll
    for (int n = 0; n < 2; n++) {
      int r = (wn & 1) * 64 + n * 16 + lr;
      int rb = r * 128, rx = (r & 7) << 4;
#pragma unroll
      for (int kh = 0; kh < 2; kh++)
        bf[n][kh] = *(const short8*)(Bx + rb + ((kh * 64 + lq * 16) ^ rx));
    }
    if (kt + 1 < nk) stageB(kt + 1, d ^ 1, 0);
    __builtin_amdgcn_s_barrier();
    asm volatile("s_waitcnt lgkmcnt(0)" ::: "memory");
    __builtin_amdgcn_s_setprio(1);
#pragma unroll
    for (int m = 0; m < 4; m++)
#pragma unroll
      for (int n = 0; n < 2; n++)
#pragma unroll
        for (int kh = 0; kh < 2; kh++)
          acc[m][n] = __builtin_amdgcn_mfma_f32_16x16x32_bf16(af[m][kh], bf[n][kh], acc[m][n], 0, 0, 0);
    __builtin_amdgcn_s_setprio(0);
    __builtin_amdgcn_s_barrier();
    // ===== phase 2: bf2-3; stage (t+1).B1; MFMA m0-3 x n2-3 =====
#pragma unroll
    for (int n = 2; n < 4; n++) {
      int r = (wn & 1) * 64 + n * 16 + lr;
      int rb = r * 128, rx = (r & 7) << 4;
#pragma unroll
      for (int kh = 0; kh < 2; kh++)
        bf[n][kh] = *(const short8*)(Bx + rb + ((kh * 64 + lq * 16) ^ rx));
    }
    if (kt + 1 < nk) stageB(kt + 1, d ^ 1, 1);
    __builtin_amdgcn_s_barrier();
    asm volatile("s_waitcnt lgkmcnt(0)" ::: "memory");
    __builtin_amdgcn_s_setprio(1);
#pragma unroll
    for (int m = 0; m < 4; m++)
#pragma unroll
      for (int n = 2; n < 4; n++)
#pragma unroll
        for (int kh = 0; kh < 2; kh++)
          acc[m][n] = __builtin_amdgcn_mfma_f32_16x16x32_bf16(af[m][kh], bf[n][kh], acc[m][n], 0, 0, 0);
    __builtin_amdgcn_s_setprio(0);
    __builtin_amdgcn_s_barrier();
    // ===== phase 3: af4-7; MFMA m4-7 x n2-3 =====
#pragma unroll
    for (int m = 0; m < 4; m++) {
      int r = 64 + m * 16 + lr;
      int rb = r * 128, rx = (r & 7) << 4;
#pragma unroll
      for (int kh = 0; kh < 2; kh++)
        af[m][kh] = *(const short8*)(Ax + rb + ((kh * 64 + lq * 16) ^ rx));
    }
    __builtin_amdgcn_s_barrier();
    asm volatile("s_waitcnt lgkmcnt(0)" ::: "memory");
    __builtin_amdgcn_s_setprio(1);
#pragma unroll
    for (int m = 0; m < 4; m++)
#pragma unroll
      for (int n = 2; n < 4; n++)
#pragma unroll
        for (int kh = 0; kh < 2; kh++)
          acc[4 + m][n] = __builtin_amdgcn_mfma_f32_16x16x32_bf16(af[m][kh], bf[n][kh], acc[4 + m][n], 0, 0, 0);
    __builtin_amdgcn_s_setprio(0);
    __builtin_amdgcn_s_barrier();
    // ===== phase 4: stage (t+2).A; MFMA m4-7 x n0-1; vmcnt =====
    if (kt + 2 < nk) stageA(kt + 2, d);
    __builtin_amdgcn_s_barrier();
    __builtin_amdgcn_s_setprio(1);
#pragma unroll
    for (int m = 0; m < 4; m++)
#pragma unroll
      for (int n = 0; n < 2; n++)
#pragma unroll
        for (int kh = 0; kh < 2; kh++)
          acc[4 + m][n] = __builtin_amdgcn_mfma_f32_16x16x32_bf16(af[m][kh], bf[n][kh], acc[4 + m][n], 0, 0, 0);
    __builtin_amdgcn_s_setprio(0);
    if (kt + 2 < nk) vm_wait<4>();
    else vm_wait<0>();
    __builtin_amdgcn_s_barrier();
  }
  // epilogue
#pragma unroll
  for (int m = 0; m < 8; m++) {
#pragma unroll
    for (int i = 0; i < 4; i++) {
      int row = m0 + wm * 128 + m * 16 + lq * 4 + i;
      size_t rb = (size_t)row * N + n0 + wn * 64 + lr;
#pragma unroll
      for (int n = 0; n < 4; n++) {
        float f = acc[m][n][i];
        if (OUT == 0) ((float*)C)[rb + n * 16] = f;
        else if (OUT == 1) ((u16*)C)[rb + n * 16] = f2bf(f);
        else {
          u16 hi = f2bf(f);
          ((u16*)C)[rb + n * 16] = hi;
          C2[rb + n * 16] = f2bf(f - bf2f(hi));
        }
      }
    }
  }
}

// ---------- 2-phase pipelined GEMM (kept for N=4096-out shapes, BN=128) ----------
template <int BN, bool OBF16>
__global__ __launch_bounds__(512, 2) void gemm_pipe(
    const u16* __restrict__ A, const u16* __restrict__ Bt, void* __restrict__ C,
    int M, int N, int K, int lda) {
  constexpr int NW = BN / 64;
  constexpr int LPT = 4 + BN / 64;
  __shared__ __attribute__((aligned(16))) u16 Asb[2][256 * 64];
  __shared__ __attribute__((aligned(16))) u16 Bsb[2][BN * 64];
  int t = threadIdx.x, l = t & 63, w = t >> 6;
  int m0 = blockIdx.y * 256, n0 = blockIdx.x * BN;
  int wm = (w >> 2) * 128, wn = (w & 3) * (BN / 4);
  f32x4 acc[8][NW] = {};
  int nk = K >> 6;

  auto stage = [&](int tt, int bb) {
    int k0 = tt << 6;
#pragma unroll
    for (int i = 0; i < 4; i++) {
      int id = i * 512 + t;
      int r = id >> 3, cb = id & 7;
      int csw = ((cb * 16) ^ ((r & 7) << 4)) >> 1;
      gl_lds16(&A[(size_t)(m0 + r) * lda + k0 + csw], &Asb[bb][id * 8]);
    }
#pragma unroll
    for (int i = 0; i < BN / 64; i++) {
      int id = i * 512 + t;
      int r = id >> 3, cb = id & 7;
      int csw = ((cb * 16) ^ ((r & 7) << 4)) >> 1;
      gl_lds16(&Bt[(size_t)(n0 + r) * K + k0 + csw], &Bsb[bb][id * 8]);
    }
  };

  stage(0, 0);
  for (int kt = 0; kt < nk; ++kt) {
    int cur = kt & 1;
    __builtin_amdgcn_sched_barrier(0);
    __builtin_amdgcn_s_barrier();
    if (kt + 1 < nk) { stage(kt + 1, cur ^ 1); vm_wait<LPT>(); }
    else vm_wait<0>();
#pragma unroll
    for (int kh = 0; kh < 2; kh++) {
      short8 af[8], bfr[NW];
#pragma unroll
      for (int m = 0; m < 8; m++) {
        int row = wm + m * 16 + (l & 15);
        int pb = (row * 128 + kh * 64 + (l >> 4) * 16) ^ ((row & 7) << 4);
        af[m] = *(const short8*)((const char*)Asb[cur] + pb);
      }
#pragma unroll
      for (int n = 0; n < NW; n++) {
        int row = wn + n * 16 + (l & 15);
        int pb = (row * 128 + kh * 64 + (l >> 4) * 16) ^ ((row & 7) << 4);
        bfr[n] = *(const short8*)((const char*)Bsb[cur] + pb);
      }
      __builtin_amdgcn_s_setprio(1);
#pragma unroll
      for (int m = 0; m < 8; m++)
#pragma unroll
        for (int n = 0; n < NW; n++)
          acc[m][n] = __builtin_amdgcn_mfma_f32_16x16x32_bf16(af[m], bfr[n], acc[m][n], 0, 0, 0);
      __builtin_amdgcn_s_setprio(0);
    }
  }
#pragma unroll
  for (int m = 0; m < 8; m++) {
#pragma unroll
    for (int i = 0; i < 4; i++) {
      int row = m0 + wm + m * 16 + (l >> 4) * 4 + i;
      size_t rb = (size_t)row * N + n0 + wn + (l & 15);
      if (OBF16) {
        u16* Cb = (u16*)C;
#pragma unroll
        for (int n = 0; n < NW; n++) Cb[rb + n * 16] = f2bf(acc[m][n][i]);
      } else {
        float* Cf = (float*)C;
#pragma unroll
        for (int n = 0; n < NW; n++) Cf[rb + n * 16] = acc[m][n][i];
      }
    }
  }
}

// ---------- flash attention (no scale, no mask), split-precision QK^T ----------
__global__ __launch_bounds__(256) void attn_kernel(
    const u16* __restrict__ qh, const u16* __restrict__ ql,
    const u16* __restrict__ kh, const u16* __restrict__ kl,
    const u16* __restrict__ vt, u16* __restrict__ out) {
  const int QS = 8192;
  __shared__ __attribute__((aligned(16))) u16 KH[64 * 128];   // [kv][d], XOR-swizzled
  __shared__ __attribute__((aligned(16))) u16 KL[64 * 128];
  __shared__ __attribute__((aligned(16))) u16 Vl[128 * 64];   // [d][kv], XOR-swizzled
  __shared__ __attribute__((aligned(16))) u16 Pl[4][16 * 72]; // per-wave [q][kv], pad 72
  int t = threadIdx.x, l = t & 63, w = t >> 6;
  int hd = blockIdx.y, q0 = blockIdx.x * 64;
  int qrow = q0 + w * 16 + (l & 15);
  size_t qoff = (size_t)qrow * QS + hd * 128 + (l >> 4) * 8;
  short8 qfh[4], qfl[4];
#pragma unroll
  for (int kc = 0; kc < 4; kc++) {
    qfh[kc] = *(const short8*)&qh[qoff + kc * 32];
    qfl[kc] = *(const short8*)&ql[qoff + kc * 32];
  }
  f32x4 accO[8] = {};
  float mrun = -__builtin_inff(), lrun = 0.f;
  for (int kv0 = 0; kv0 < 2048; kv0 += 64) {
#pragma unroll
    for (int i = 0; i < 4; i++) {
      int ci = i * 256 + t;
      int row = ci >> 4;
      int cb = (ci & 15) ^ (row & 7);
      size_t src = (size_t)(kv0 + row) * QS + hd * 128 + cb * 8;
      gl_lds16(&kh[src], &KH[ci * 8]);
      gl_lds16(&kl[src], &KL[ci * 8]);
    }
#pragma unroll
    for (int i = 0; i < 4; i++) {
      int ci = i * 256 + t;
      int row = ci >> 3;
      int cb = (ci & 7) ^ (row & 7);
      gl_lds16(&vt[((size_t)hd * 128 + row) * 2048 + kv0 + cb * 8], &Vl[ci * 8]);
    }
    __syncthreads();
    f32x4 accS[4];
#pragma unroll
    for (int mm = 0; mm < 4; mm++) {
      accS[mm] = (f32x4){0.f, 0.f, 0.f, 0.f};
#pragma unroll
      for (int kc = 0; kc < 4; kc++) {
        int rowk = mm * 16 + (l & 15);
        int logb = rowk * 256 + kc * 64 + (l >> 4) * 16;
        int phys = logb ^ ((rowk & 7) << 4);
        short8 a_h = *(const short8*)((const char*)KH + phys);
        short8 a_l = *(const short8*)((const char*)KL + phys);
        accS[mm] = __builtin_amdgcn_mfma_f32_16x16x32_bf16(a_h, qfh[kc], accS[mm], 0, 0, 0);
        accS[mm] = __builtin_amdgcn_mfma_f32_16x16x32_bf16(a_h, qfl[kc], accS[mm], 0, 0, 0);
        accS[mm] = __builtin_amdgcn_mfma_f32_16x16x32_bf16(a_l, qfh[kc], accS[mm], 0, 0, 0);
      }
    }
    float tmax = -__builtin_inff();
#pragma unroll
    for (int mm = 0; mm < 4; mm++)
      tmax = fmaxf(tmax, fmaxf(fmaxf(accS[mm][0], accS[mm][1]), fmaxf(accS[mm][2], accS[mm][3])));
    tmax = fmaxf(tmax, __shfl_xor(tmax, 16));
    tmax = fmaxf(tmax, __shfl_xor(tmax, 32));
    float mnew = fmaxf(mrun, tmax);
    float scale = expf(mrun - mnew);
    float psum = 0.f;
#pragma unroll
    for (int mm = 0; mm < 4; mm++) {
      float p0 = expf(accS[mm][0] - mnew), p1 = expf(accS[mm][1] - mnew);
      float p2 = expf(accS[mm][2] - mnew), p3 = expf(accS[mm][3] - mnew);
      psum += (p0 + p1) + (p2 + p3);
      ushort4 pk;
      pk.x = f2bf(p0); pk.y = f2bf(p1); pk.z = f2bf(p2); pk.w = f2bf(p3);
      *(ushort4*)&Pl[w][(l & 15) * 72 + mm * 16 + (l >> 4) * 4] = pk;
    }
    psum += __shfl_xor(psum, 16);
    psum += __shfl_xor(psum, 32);
    lrun = lrun * scale + psum;
    mrun = mnew;
#pragma unroll
    for (int mm = 0; mm < 8; mm++) accO[mm] = accO[mm] * scale;
#pragma unroll
    for (int kc2 = 0; kc2 < 2; kc2++) {
      short8 bp = *(const short8*)((const char*)&Pl[w][0] + (l & 15) * 144 + kc2 * 64 + (l >> 4) * 16);
#pragma unroll
      for (int mm = 0; mm < 8; mm++) {
        int rowd = mm * 16 + (l & 15);
        int logb = rowd * 128 + kc2 * 64 + (l >> 4) * 16;
        int phys = logb ^ ((rowd & 7) << 4);
        short8 av = *(const short8*)((const char*)Vl + phys);
        accO[mm] = __builtin_amdgcn_mfma_f32_16x16x32_bf16(av, bp, accO[mm], 0, 0, 0);
      }
    }
    __syncthreads();
  }
  float rinv = 1.f / lrun;
#pragma unroll
  for (int mm = 0; mm < 8; mm++) {
    ushort4 pk;
    pk.x = f2bf(accO[mm][0] * rinv); pk.y = f2bf(accO[mm][1] * rinv);
    pk.z = f2bf(accO[mm][2] * rinv); pk.w = f2bf(accO[mm][3] * rinv);
    *(ushort4*)&out[(size_t)qrow * 4096 + hd * 128 + mm * 16 + (l >> 4) * 4] = pk;
  }
}

// ---------- silu-mul on fused x1x3 [2048][22016]: x1 *= silu(x3) in place ----------
__global__ __launch_bounds__(256) void silumul_kernel(u16* __restrict__ x1x3) {
  int cg = blockIdx.x * 256 + threadIdx.x;
  if (cg >= 1376) return;
  size_t base = (size_t)blockIdx.y * 22016 + cg * 8;
  uint4 a = *(const uint4*)&x1x3[base];
  uint4 b = *(const uint4*)&x1x3[base + 11008];
  unsigned int* ap = (unsigned int*)&a;
  const unsigned int* bp = (const unsigned int*)&b;
#pragma unroll
  for (int j = 0; j < 4; j++) {
    float a0 = bf2f(ap[j] & 0xffff), a1 = bf2f(ap[j] >> 16);
    float b0 = bf2f(bp[j] & 0xffff), b1 = bf2f(bp[j] >> 16);
    float r0 = a0 * (b0 / (1.f + expf(-b0)));
    float r1 = a1 * (b1 / (1.f + expf(-b1)));
    ap[j] = (unsigned int)f2bf(r0) | ((unsigned int)f2bf(r1) << 16);
  }
  *(uint4*)&x1x3[base] = a;
}

// ---------- launch ----------
extern "C" void kernel_launch(void* const* d_in, const int* in_sizes, int n_in,
                              void* d_out, int out_size, void* d_ws, size_t ws_size,
                              hipStream_t stream) {
  const float* x      = (const float*)d_in[0];
  const float* wq     = (const float*)d_in[1];
  const float* wk     = (const float*)d_in[2];
  const float* wv     = (const float*)d_in[3];
  const float* wo     = (const float*)d_in[4];
  const float* w1     = (const float*)d_in[5];
  const float* w2     = (const float*)d_in[6];
  const float* w3     = (const float*)d_in[7];
  const float* g_attn = (const float*)d_in[8];
  const float* g_ffn  = (const float*)d_in[9];

  char* ws = (char*)d_ws;
  // region layout (total ~383 MB)
  char* R0 = ws;                                   // 180.4MB rotating weights (hi)
  char* R1 = R0 + (size_t)22016 * 4096 * 2;        // 67.1MB wqk_lo; later xo,h2
  char* R2 = R1 + (size_t)8192 * 4096 * 2;         // 33.6MB h_hi,h_lo
  char* R3 = R2 + (size_t)2 * 2048 * 4096 * 2;     // 67.1MB qk hi/lo; later x1x3 (spans R4)
  char* R4 = R3 + (size_t)2 * 2048 * 8192 * 2;     // 33.6MB v,vT; ao over v
  char* RT = R4 + (size_t)2 * 2048 * 4096 * 2;     // 1MB rope table
  (void)ws_size; (void)in_sizes; (void)n_in; (void)out_size;

  u16* wA    = (u16*)R0;
  u16* wB    = (u16*)R1;
  u16* h_hi  = (u16*)R2;
  u16* h_lo  = (u16*)(R2 + (size_t)2048 * 4096 * 2);
  u16* qk_hi = (u16*)R3;
  u16* qk_lo = (u16*)(R3 + (size_t)2048 * 8192 * 2);
  u16* v     = (u16*)R4;
  u16* vT    = (u16*)(R4 + (size_t)2048 * 4096 * 2);
  u16* ao    = (u16*)R4;                            // over v (dead after vtrans)
  float* xo  = (float*)R1;                          // wB dead after QK GEMM
  u16* h2    = (u16*)(R1 + (size_t)2048 * 4096 * 4);
  u16* x1x3  = (u16*)R3;                            // qk dead after attn; spans into R4
  float* tab = (float*)RT;

  dim3 tb(32, 8);
  dim3 g44(4096 / 32, 4096 / 32);

  rope_table_kernel<<<512, 256, 0, stream>>>(tab);
  rmsnorm_kernel<true><<<2048, 256, 0, stream>>>(x, g_attn, h_hi, h_lo);
  // fused Q|K projection: one plain GEMM over K'=12288 (TRIK split product)
  tconv_split_kernel<<<g44, tb, 0, stream>>>(wq, wA, wB, 4096, 4096);
  tconv_split_kernel<<<g44, tb, 0, stream>>>(wk, wA + (size_t)4096 * 4096, wB + (size_t)4096 * 4096, 4096, 4096);
  gemm8_kernel<2, true><<<dim3(32, 8), 512, 0, stream>>>(
      h_hi, h_lo, wA, wB, qk_hi, qk_lo, 2048, 8192, 12288, 4096, 4096);
  rope_inplace_kernel<<<32768, 256, 0, stream>>>(qk_hi, qk_lo, tab);
  // V projection (plain)
  tconv_kernel<<<g44, tb, 0, stream>>>(wv, wA, 4096, 4096);
  gemm_pipe<128, true><<<dim3(32, 8), 512, 0, stream>>>(h_hi, wA, v, 2048, 4096, 4096, 4096);
  vtrans_kernel<<<dim3(64, 4, 32), tb, 0, stream>>>(v, vT);
  // attention
  attn_kernel<<<dim3(32, 32), 256, 0, stream>>>(qk_hi, qk_lo, qk_hi + 4096, qk_lo + 4096, vT, ao);
  // xo = ao @ wo (f32)
  tconv_kernel<<<g44, tb, 0, stream>>>(wo, wA, 4096, 4096);
  gemm_pipe<128, false><<<dim3(32, 8), 512, 0, stream>>>(ao, wA, xo, 2048, 4096, 4096, 4096);
  rmsnorm_kernel<false><<<2048, 256, 0, stream>>>(xo, g_ffn, h2, nullptr);
  // fused FFN up: x1|x3 = h2 @ [w1 w3]  (8-phase, N=22016)
  tconv_kernel<<<dim3(344, 128), tb, 0, stream>>>(w1, wA, 4096, 11008);
  tconv_kernel<<<dim3(344, 128), tb, 0, stream>>>(w3, wA + (size_t)11008 * 4096, 4096, 11008);
  gemm8_kernel<1, false><<<dim3(86, 8), 512, 0, stream>>>(
      h2, nullptr, wA, nullptr, x1x3, nullptr, 2048, 22016, 4096, 4096, 4096);
  silumul_kernel<<<dim3(6, 2048), 256, 0, stream>>>(x1x3);
  // out = (x1*silu(x3)) @ w2
  tconv_kernel<<<dim3(128, 344), tb, 0, stream>>>(w2, wA, 11008, 4096);
  gemm_pipe<128, false><<<dim3(32, 8), 512, 0, stream>>>(x1x3, wA, (float*)d_out, 2048, 4096, 11008, 22016);
}

// Round 5
// 1718.031 us; speedup vs baseline: 1.2074x; 1.1183x over previous
//
#include <hip/hip_runtime.h>
#include <math.h>

// ---------- types / helpers ----------
typedef unsigned short u16;
typedef short short8 __attribute__((ext_vector_type(8)));
typedef float f32x4 __attribute__((ext_vector_type(4)));

#define DEV static __device__ __forceinline__

DEV float bf2f(u16 h) { union { unsigned int u; float f; } v; v.u = ((unsigned int)h) << 16; return v.f; }
DEV u16 f2bf(float f) {
  union { float f; unsigned int u; } v; v.f = f;
  unsigned int r = v.u + 0x7FFFu + ((v.u >> 16) & 1u);  // RNE
  return (u16)(r >> 16);
}

DEV void gl_lds16(const void* g, void* l) {
  __builtin_amdgcn_global_load_lds(
      (const __attribute__((address_space(1))) unsigned int*)g,
      (__attribute__((address_space(3))) unsigned int*)l, 16, 0, 0);
}

template <int N> DEV void vm_wait() {
  if constexpr (N == 0) asm volatile("s_waitcnt vmcnt(0)" ::: "memory");
  else if constexpr (N == 6) asm volatile("s_waitcnt vmcnt(6)" ::: "memory");
  else if constexpr (N == 8) asm volatile("s_waitcnt vmcnt(8)" ::: "memory");
  else static_assert(N == 0 || N == 6 || N == 8, "add literal");
}

DEV void lgkm0_pin() {
  asm volatile("s_waitcnt lgkmcnt(0)" ::: "memory");
  __builtin_amdgcn_sched_barrier(0);
}

// XCD-aware block swizzle. gx%8==0: each XCD owns a bx-chunk (x all by).
// else: each XCD owns a contiguous swz-chunk (by-major). Both bijective.
DEV void xcd_swizzle(int& bx, int& by) {
  int gx = gridDim.x, gy = gridDim.y;
  int lin = by * gx + bx;
  int xcd = lin & 7, i = lin >> 3;
  if ((gx & 7) == 0) {
    int cx = gx >> 3;
    bx = xcd * cx + i % cx;
    by = i / cx;
  } else {
    int cpx = (gx * gy) >> 3;
    int swz = xcd * cpx + i;
    bx = swz % gx;
    by = swz / gx;
  }
}

// ---------- RMSNorm: f32 [2048][4096] -> bf16 (optionally split hi/lo) ----------
template <bool SPLIT>
__global__ __launch_bounds__(256) void rmsnorm_kernel(
    const float* __restrict__ x, const float* __restrict__ g,
    u16* __restrict__ oh, u16* __restrict__ ol) {
  int row = blockIdx.x, t = threadIdx.x;
  const float* xr = x + (size_t)row * 4096;
  float4 vals[4];
  float s = 0.f;
#pragma unroll
  for (int i = 0; i < 4; i++) {
    vals[i] = ((const float4*)xr)[t + i * 256];
    s += vals[i].x * vals[i].x + vals[i].y * vals[i].y + vals[i].z * vals[i].z + vals[i].w * vals[i].w;
  }
#pragma unroll
  for (int m = 1; m < 64; m <<= 1) s += __shfl_xor(s, m);
  __shared__ float red[4];
  if ((t & 63) == 0) red[t >> 6] = s;
  __syncthreads();
  s = red[0] + red[1] + red[2] + red[3];
  float rinv = rsqrtf(s * (1.f / 4096.f) + 1.1920929e-07f);
#pragma unroll
  for (int i = 0; i < 4; i++) {
    float4 gv = ((const float4*)g)[t + i * 256];
    float4 v = vals[i];
    float f[4] = {v.x * rinv * gv.x, v.y * rinv * gv.y, v.z * rinv * gv.z, v.w * rinv * gv.w};
    ushort4 rh, rl;
    u16* hp = (u16*)&rh; u16* lp = (u16*)&rl;
#pragma unroll
    for (int j = 0; j < 4; j++) {
      u16 hi = f2bf(f[j]);
      hp[j] = hi;
      if (SPLIT) lp[j] = f2bf(f[j] - bf2f(hi));
    }
    ((ushort4*)(oh + (size_t)row * 4096))[t + i * 256] = rh;
    if (SPLIT) ((ushort4*)(ol + (size_t)row * 4096))[t + i * 256] = rl;
  }
}

// ---------- transpose-convert: w f32 [K][N] -> wT bf16 [N][K] ----------
__global__ void tconv_kernel(const float* __restrict__ in, u16* __restrict__ out, int K, int N) {
  __shared__ float tile[32][33];
  int k0 = blockIdx.y * 32, n0 = blockIdx.x * 32;
  int tx = threadIdx.x, ty = threadIdx.y;  // (32,8)
#pragma unroll
  for (int i = 0; i < 4; i++)
    tile[ty + 8 * i][tx] = in[(size_t)(k0 + ty + 8 * i) * N + n0 + tx];
  __syncthreads();
#pragma unroll
  for (int i = 0; i < 4; i++) {
    int n = ty + 8 * i;
    out[(size_t)(n0 + n) * K + k0 + tx] = f2bf(tile[tx][n]);
  }
}

// ---------- transpose-convert split: w f32 [K][N] -> hi/lo bf16 [N][K] ----------
__global__ void tconv_split_kernel(const float* __restrict__ in, u16* __restrict__ oh,
                                   u16* __restrict__ ol, int K, int N) {
  __shared__ float tile[32][33];
  int k0 = blockIdx.y * 32, n0 = blockIdx.x * 32;
  int tx = threadIdx.x, ty = threadIdx.y;  // (32,8)
#pragma unroll
  for (int i = 0; i < 4; i++)
    tile[ty + 8 * i][tx] = in[(size_t)(k0 + ty + 8 * i) * N + n0 + tx];
  __syncthreads();
#pragma unroll
  for (int i = 0; i < 4; i++) {
    int n = ty + 8 * i;
    float f = tile[tx][n];
    u16 hi = f2bf(f);
    size_t idx = (size_t)(n0 + n) * K + k0 + tx;
    oh[idx] = hi;
    ol[idx] = f2bf(f - bf2f(hi));
  }
}

// ---------- bf16 transpose v [2048][4096] -> vT [32][128][2048] ----------
__global__ void vtrans_kernel(const u16* __restrict__ v, u16* __restrict__ vt) {
  __shared__ u16 tile[32][33];
  int s0 = blockIdx.x * 32, d0 = blockIdx.y * 32, hd = blockIdx.z;
  int tx = threadIdx.x, ty = threadIdx.y;  // (32,8)
#pragma unroll
  for (int i = 0; i < 4; i++)
    tile[ty + 8 * i][tx] = v[(size_t)(s0 + ty + 8 * i) * 4096 + hd * 128 + d0 + tx];
  __syncthreads();
#pragma unroll
  for (int i = 0; i < 4; i++) {
    int d = ty + 8 * i;
    vt[((size_t)hd * 128 + d0 + d) * 2048 + s0 + tx] = tile[tx][d];
  }
}

// ---------- RoPE cos/sin table (double precision): tab[s][j] = {cos,sin} ----------
__global__ __launch_bounds__(256) void rope_table_kernel(float* __restrict__ tab) {
  int i = blockIdx.x * 256 + threadIdx.x;  // 2048*64
  int j = i & 63, s = i >> 6;
  double freq = pow(10000.0, -(double)j / 64.0);
  double ang = (double)s * freq;
  tab[i * 2] = (float)cos(ang);
  tab[i * 2 + 1] = (float)sin(ang);
}

// ---------- RoPE in place on (hi,lo) [2048][8192]; one wave owns one 128-col slot ----------
__global__ __launch_bounds__(256) void rope_inplace_kernel(
    u16* hi, u16* lo, const float* __restrict__ tab) {
  int idx = blockIdx.x * 256 + threadIdx.x;  // (s, slot6, j)
  int j = idx & 63, hd = (idx >> 6) & 63, s = idx >> 12;
  size_t base = (size_t)s * 8192 + hd * 128;
  float xe = bf2f(hi[base + 2 * j]) + bf2f(lo[base + 2 * j]);
  float xo = bf2f(hi[base + 2 * j + 1]) + bf2f(lo[base + 2 * j + 1]);
  float cs = tab[(s * 64 + j) * 2], sn = tab[(s * 64 + j) * 2 + 1];
  float r0 = xe * cs - xo * sn;
  float r1 = xe * sn + xo * cs;
  u16 h0 = f2bf(r0), h1 = f2bf(r1);
  hi[base + j] = h0;      lo[base + j] = f2bf(r0 - bf2f(h0));
  hi[base + 64 + j] = h1; lo[base + 64 + j] = f2bf(r1 - bf2f(h1));
}

// ---------- 8-phase 256x256 GEMM, 2-tiles-ahead staging ----------
// A bf16 [M][lda] @ Bt bf16 [N][ldb] -> C [M][N]. 512 thr = 8 waves (2M x 4N).
// TRIK: K' = 3*Kseg, per-segment operand select (split-bf16 3-product as one GEMM).
// Staging: tile t+2 -> buffer (t&1): B at ph3 (after t's B-reads), A at ph4
// (after t's A-reads); vmcnt(8) at ph4 leaves exactly (t+2)'s 8 loads in flight
// => t+1's loads (issued at t-1.ph3/4, ~5 phases earlier) proven landed.
template <int OUT, bool TRIK>  // OUT: 0=f32, 1=bf16, 2=split hi/lo
__global__ __launch_bounds__(512, 2) void gemm8_kernel(
    const u16* __restrict__ A, const u16* __restrict__ A2,
    const u16* __restrict__ B, const u16* __restrict__ B2,
    void* __restrict__ C, u16* __restrict__ C2,
    int M, int N, int K, int lda, int ldb) {
  __shared__ __attribute__((aligned(16))) u16 As[2][2][128 * 64];
  __shared__ __attribute__((aligned(16))) u16 Bs[2][2][128 * 64];
  int t = threadIdx.x, l = t & 63, w = t >> 6;
  int bx = blockIdx.x, by = blockIdx.y;
  xcd_swizzle(bx, by);
  int m0 = by * 256, n0 = bx * 256;
  int wm = w >> 2, wn = w & 3, bh = wn >> 1;
  f32x4 acc[8][4] = {};
  int nk = K >> 6;

  auto stageA = [&](int kt, int dd) {  // both halves, 4 loads/thread
    const u16* Ab = A; int kc = kt << 6;
    if (TRIK) { int seg = kt >> 6; Ab = (seg == 1) ? A2 : A; kc = (kt & 63) << 6; }
#pragma unroll
    for (int i = 0; i < 4; i++) {
      int id = i * 512 + t;
      int hh = id >> 10, idc = id & 1023;
      int r = idc >> 3, cb = idc & 7;
      int csw = ((cb * 16) ^ ((r & 7) << 4)) >> 1;
      gl_lds16(&Ab[(size_t)(m0 + hh * 128 + r) * lda + kc + csw], &As[dd][hh][idc * 8]);
    }
  };
  auto stageB = [&](int kt, int dd) {  // both halves, 4 loads/thread
    const u16* Bb = B; int kc = kt << 6;
    if (TRIK) { int seg = kt >> 6; Bb = (seg == 2) ? B2 : B; kc = (kt & 63) << 6; }
#pragma unroll
    for (int i = 0; i < 4; i++) {
      int id = i * 512 + t;
      int hh = id >> 10, idc = id & 1023;
      int r = idc >> 3, cb = idc & 7;
      int csw = ((cb * 16) ^ ((r & 7) << 4)) >> 1;
      gl_lds16(&Bb[(size_t)(n0 + hh * 128 + r) * ldb + kc + csw], &Bs[dd][hh][idc * 8]);
    }
  };

  // prologue: stage tiles 0 and 1 fully; wait tile0 landed (tile1 in flight)
  stageB(0, 0); stageA(0, 0);
  stageB(1, 1); stageA(1, 1);
  vm_wait<8>();
  __builtin_amdgcn_s_barrier();

  short8 af[4][2], bf[4][2];
  int lq = l >> 4, lr = l & 15;
  for (int kt = 0; kt < nk; ++kt) {
    int d = kt & 1;
    const char* Ax = (const char*)As[d][wm];
    const char* Bx = (const char*)Bs[d][bh];
    // ===== phase 1: read af0-3 + bf0-1; MFMA m0-3 x n0-1 =====
#pragma unroll
    for (int m = 0; m < 4; m++) {
      int r = m * 16 + lr;
      int rb = r * 128, rx = (r & 7) << 4;
#pragma unroll
      for (int kh = 0; kh < 2; kh++)
        af[m][kh] = *(const short8*)(Ax + rb + ((kh * 64 + lq * 16) ^ rx));
    }
#pragma unroll
    for (int n = 0; n < 2; n++) {
      int r = (wn & 1) * 64 + n * 16 + lr;
      int rb = r * 128, rx = (r & 7) << 4;
#pragma unroll
      for (int kh = 0; kh < 2; kh++)
        bf[n][kh] = *(const short8*)(Bx + rb + ((kh * 64 + lq * 16) ^ rx));
    }
    __builtin_amdgcn_s_barrier();
    lgkm0_pin();
    __builtin_amdgcn_s_setprio(1);
#pragma unroll
    for (int m = 0; m < 4; m++)
#pragma unroll
      for (int n = 0; n < 2; n++)
#pragma unroll
        for (int kh = 0; kh < 2; kh++)
          acc[m][n] = __builtin_amdgcn_mfma_f32_16x16x32_bf16(af[m][kh], bf[n][kh], acc[m][n], 0, 0, 0);
    __builtin_amdgcn_s_setprio(0);
    __builtin_amdgcn_s_barrier();
    // ===== phase 2: read bf2-3; MFMA m0-3 x n2-3 =====
#pragma unroll
    for (int n = 2; n < 4; n++) {
      int r = (wn & 1) * 64 + n * 16 + lr;
      int rb = r * 128, rx = (r & 7) << 4;
#pragma unroll
      for (int kh = 0; kh < 2; kh++)
        bf[n][kh] = *(const short8*)(Bx + rb + ((kh * 64 + lq * 16) ^ rx));
    }
    __builtin_amdgcn_s_barrier();
    lgkm0_pin();
    __builtin_amdgcn_s_setprio(1);
#pragma unroll
    for (int m = 0; m < 4; m++)
#pragma unroll
      for (int n = 2; n < 4; n++)
#pragma unroll
        for (int kh = 0; kh < 2; kh++)
          acc[m][n] = __builtin_amdgcn_mfma_f32_16x16x32_bf16(af[m][kh], bf[n][kh], acc[m][n], 0, 0, 0);
    __builtin_amdgcn_s_setprio(0);
    __builtin_amdgcn_s_barrier();  // guards ph3's B-stage vs ph2's B-reads
    // ===== phase 3: read af4-7; stage (t+2).B; MFMA m4-7 x n2-3 =====
#pragma unroll
    for (int m = 0; m < 4; m++) {
      int r = 64 + m * 16 + lr;
      int rb = r * 128, rx = (r & 7) << 4;
#pragma unroll
      for (int kh = 0; kh < 2; kh++)
        af[m][kh] = *(const short8*)(Ax + rb + ((kh * 64 + lq * 16) ^ rx));
    }
    if (kt + 2 < nk) stageB(kt + 2, d);
    __builtin_amdgcn_s_barrier();
    lgkm0_pin();
    __builtin_amdgcn_s_setprio(1);
#pragma unroll
    for (int m = 0; m < 4; m++)
#pragma unroll
      for (int n = 2; n < 4; n++)
#pragma unroll
        for (int kh = 0; kh < 2; kh++)
          acc[4 + m][n] = __builtin_amdgcn_mfma_f32_16x16x32_bf16(af[m][kh], bf[n][kh], acc[4 + m][n], 0, 0, 0);
    __builtin_amdgcn_s_setprio(0);
    __builtin_amdgcn_s_barrier();  // guards ph4's A-stage vs ph3's A-reads
    // ===== phase 4: stage (t+2).A; MFMA m4-7 x n0-1; vmcnt =====
    if (kt + 2 < nk) stageA(kt + 2, d);
    __builtin_amdgcn_s_barrier();
    __builtin_amdgcn_s_setprio(1);
#pragma unroll
    for (int m = 0; m < 4; m++)
#pragma unroll
      for (int n = 0; n < 2; n++)
#pragma unroll
        for (int kh = 0; kh < 2; kh++)
          acc[4 + m][n] = __builtin_amdgcn_mfma_f32_16x16x32_bf16(af[m][kh], bf[n][kh], acc[4 + m][n], 0, 0, 0);
    __builtin_amdgcn_s_setprio(0);
    if (kt + 2 < nk) vm_wait<8>();
    else vm_wait<0>();
    __builtin_amdgcn_s_barrier();
  }
  // epilogue
#pragma unroll
  for (int m = 0; m < 8; m++) {
#pragma unroll
    for (int i = 0; i < 4; i++) {
      int row = m0 + wm * 128 + m * 16 + lq * 4 + i;
      size_t rb = (size_t)row * N + n0 + wn * 64 + lr;
#pragma unroll
      for (int n = 0; n < 4; n++) {
        float f = acc[m][n][i];
        if (OUT == 0) ((float*)C)[rb + n * 16] = f;
        else if (OUT == 1) ((u16*)C)[rb + n * 16] = f2bf(f);
        else {
          u16 hi = f2bf(f);
          ((u16*)C)[rb + n * 16] = hi;
          C2[rb + n * 16] = f2bf(f - bf2f(hi));
        }
      }
    }
  }
}

// ---------- 2-phase 128x256 GEMM for N=4096 shapes (grid fills all CUs) ----------
// 512 thr = 8 waves (2M x 4N), wave-out 64x64. A double-buffered, B TRIPLE-buffered
// so (t+2).B stages race-free in ph1; (t+2).A in ph2 (after ph1-barrier guards
// t's A-reads). vmcnt(6) at ph2-end leaves exactly (t+2)'s 6 loads in flight.
template <int OUT>  // 0=f32, 1=bf16
__global__ __launch_bounds__(512, 2) void gemm8n_kernel(
    const u16* __restrict__ A, const u16* __restrict__ B, void* __restrict__ C,
    int M, int N, int K, int lda, int ldb) {
  __shared__ __attribute__((aligned(16))) u16 As[2][128 * 64];
  __shared__ __attribute__((aligned(16))) u16 Bs3[3][256 * 64];
  int t = threadIdx.x, l = t & 63, w = t >> 6;
  int bx = blockIdx.x, by = blockIdx.y;
  xcd_swizzle(bx, by);
  int m0 = by * 128, n0 = bx * 256;
  int wm = w >> 2, wn = w & 3;
  f32x4 acc[4][4] = {};
  int nk = K >> 6;

  auto stageA = [&](int kt, int dd) {  // 2 loads/thread
    int kc = kt << 6;
#pragma unroll
    for (int i = 0; i < 2; i++) {
      int id = i * 512 + t;
      int r = id >> 3, cb = id & 7;
      int csw = ((cb * 16) ^ ((r & 7) << 4)) >> 1;
      gl_lds16(&A[(size_t)(m0 + r) * lda + kc + csw], &As[dd][id * 8]);
    }
  };
  auto stageB = [&](int kt, int bb) {  // 4 loads/thread
    int kc = kt << 6;
#pragma unroll
    for (int i = 0; i < 4; i++) {
      int id = i * 512 + t;
      int r = id >> 3, cb = id & 7;
      int csw = ((cb * 16) ^ ((r & 7) << 4)) >> 1;
      gl_lds16(&B[(size_t)(n0 + r) * ldb + kc + csw], &Bs3[bb][id * 8]);
    }
  };

  stageB(0, 0); stageA(0, 0);
  stageB(1, 1); stageA(1, 1);
  vm_wait<6>();
  __builtin_amdgcn_s_barrier();

  short8 af[4][2], bf[4][2];
  int lq = l >> 4, lr = l & 15;
  int bb = 0;  // kt % 3
  for (int kt = 0; kt < nk; ++kt) {
    int d = kt & 1;
    const char* Ax = (const char*)As[d];
    const char* Bx = (const char*)Bs3[bb];
    int bb2 = bb + 2; if (bb2 >= 3) bb2 -= 3;  // (kt+2)%3
    // ===== phase 1: read af0-3 + bf0-1; stage (t+2).B; MFMA m0-3 x n0-1 =====
#pragma unroll
    for (int m = 0; m < 4; m++) {
      int r = wm * 64 + m * 16 + lr;
      int rb = r * 128, rx = (r & 7) << 4;
#pragma unroll
      for (int kh = 0; kh < 2; kh++)
        af[m][kh] = *(const short8*)(Ax + rb + ((kh * 64 + lq * 16) ^ rx));
    }
#pragma unroll
    for (int n = 0; n < 2; n++) {
      int r = wn * 64 + n * 16 + lr;
      int rb = r * 128, rx = (r & 7) << 4;
#pragma unroll
      for (int kh = 0; kh < 2; kh++)
        bf[n][kh] = *(const short8*)(Bx + rb + ((kh * 64 + lq * 16) ^ rx));
    }
    if (kt + 2 < nk) stageB(kt + 2, bb2);
    __builtin_amdgcn_s_barrier();
    lgkm0_pin();
    __builtin_amdgcn_s_setprio(1);
#pragma unroll
    for (int m = 0; m < 4; m++)
#pragma unroll
      for (int n = 0; n < 2; n++)
#pragma unroll
        for (int kh = 0; kh < 2; kh++)
          acc[m][n] = __builtin_amdgcn_mfma_f32_16x16x32_bf16(af[m][kh], bf[n][kh], acc[m][n], 0, 0, 0);
    __builtin_amdgcn_s_setprio(0);
    __builtin_amdgcn_s_barrier();  // guards ph2's A-stage vs ph1's A-reads
    // ===== phase 2: read bf2-3; stage (t+2).A; MFMA m0-3 x n2-3; vmcnt =====
#pragma unroll
    for (int n = 2; n < 4; n++) {
      int r = wn * 64 + n * 16 + lr;
      int rb = r * 128, rx = (r & 7) << 4;
#pragma unroll
      for (int kh = 0; kh < 2; kh++)
        bf[n][kh] = *(const short8*)(Bx + rb + ((kh * 64 + lq * 16) ^ rx));
    }
    if (kt + 2 < nk) stageA(kt + 2, d);
    __builtin_amdgcn_s_barrier();
    lgkm0_pin();
    __builtin_amdgcn_s_setprio(1);
#pragma unroll
    for (int m = 0; m < 4; m++)
#pragma unroll
      for (int n = 2; n < 4; n++)
#pragma unroll
        for (int kh = 0; kh < 2; kh++)
          acc[m][n] = __builtin_amdgcn_mfma_f32_16x16x32_bf16(af[m][kh], bf[n][kh], acc[m][n], 0, 0, 0);
    __builtin_amdgcn_s_setprio(0);
    if (kt + 2 < nk) vm_wait<6>();
    else vm_wait<0>();
    __builtin_amdgcn_s_barrier();
    bb = bb + 1; if (bb >= 3) bb -= 3;
  }
  // epilogue: wave-out 64x64 at (m0 + wm*64, n0 + wn*64)
#pragma unroll
  for (int m = 0; m < 4; m++) {
#pragma unroll
    for (int i = 0; i < 4; i++) {
      int row = m0 + wm * 64 + m * 16 + lq * 4 + i;
      size_t rb = (size_t)row * N + n0 + wn * 64 + lr;
#pragma unroll
      for (int n = 0; n < 4; n++) {
        float f = acc[m][n][i];
        if (OUT == 0) ((float*)C)[rb + n * 16] = f;
        else ((u16*)C)[rb + n * 16] = f2bf(f);
      }
    }
  }
}

// ---------- flash attention (no scale, no mask), split-precision QK^T ----------
__global__ __launch_bounds__(256) void attn_kernel(
    const u16* __restrict__ qh, const u16* __restrict__ ql,
    const u16* __restrict__ kh, const u16* __restrict__ kl,
    const u16* __restrict__ vt, u16* __restrict__ out) {
  const int QS = 8192;
  __shared__ __attribute__((aligned(16))) u16 KH[64 * 128];   // [kv][d], XOR-swizzled
  __shared__ __attribute__((aligned(16))) u16 KL[64 * 128];
  __shared__ __attribute__((aligned(16))) u16 Vl[128 * 64];   // [d][kv], XOR-swizzled
  __shared__ __attribute__((aligned(16))) u16 Pl[4][16 * 72]; // per-wave [q][kv], pad 72
  int t = threadIdx.x, l = t & 63, w = t >> 6;
  int hd = blockIdx.y, q0 = blockIdx.x * 64;
  int qrow = q0 + w * 16 + (l & 15);
  size_t qoff = (size_t)qrow * QS + hd * 128 + (l >> 4) * 8;
  short8 qfh[4], qfl[4];
#pragma unroll
  for (int kc = 0; kc < 4; kc++) {
    qfh[kc] = *(const short8*)&qh[qoff + kc * 32];
    qfl[kc] = *(const short8*)&ql[qoff + kc * 32];
  }
  f32x4 accO[8] = {};
  float mrun = -__builtin_inff(), lrun = 0.f;
  for (int kv0 = 0; kv0 < 2048; kv0 += 64) {
#pragma unroll
    for (int i = 0; i < 4; i++) {
      int ci = i * 256 + t;
      int row = ci >> 4;
      int cb = (ci & 15) ^ (row & 7);
      size_t src = (size_t)(kv0 + row) * QS + hd * 128 + cb * 8;
      gl_lds16(&kh[src], &KH[ci * 8]);
      gl_lds16(&kl[src], &KL[ci * 8]);
    }
#pragma unroll
    for (int i = 0; i < 4; i++) {
      int ci = i * 256 + t;
      int row = ci >> 3;
      int cb = (ci & 7) ^ (row & 7);
      gl_lds16(&vt[((size_t)hd * 128 + row) * 2048 + kv0 + cb * 8], &Vl[ci * 8]);
    }
    __syncthreads();
    f32x4 accS[4];
#pragma unroll
    for (int mm = 0; mm < 4; mm++) {
      accS[mm] = (f32x4){0.f, 0.f, 0.f, 0.f};
#pragma unroll
      for (int kc = 0; kc < 4; kc++) {
        int rowk = mm * 16 + (l & 15);
        int logb = rowk * 256 + kc * 64 + (l >> 4) * 16;
        int phys = logb ^ ((rowk & 7) << 4);
        short8 a_h = *(const short8*)((const char*)KH + phys);
        short8 a_l = *(const short8*)((const char*)KL + phys);
        accS[mm] = __builtin_amdgcn_mfma_f32_16x16x32_bf16(a_h, qfh[kc], accS[mm], 0, 0, 0);
        accS[mm] = __builtin_amdgcn_mfma_f32_16x16x32_bf16(a_h, qfl[kc], accS[mm], 0, 0, 0);
        accS[mm] = __builtin_amdgcn_mfma_f32_16x16x32_bf16(a_l, qfh[kc], accS[mm], 0, 0, 0);
      }
    }
    float tmax = -__builtin_inff();
#pragma unroll
    for (int mm = 0; mm < 4; mm++)
      tmax = fmaxf(tmax, fmaxf(fmaxf(accS[mm][0], accS[mm][1]), fmaxf(accS[mm][2], accS[mm][3])));
    tmax = fmaxf(tmax, __shfl_xor(tmax, 16));
    tmax = fmaxf(tmax, __shfl_xor(tmax, 32));
    float mnew = fmaxf(mrun, tmax);
    float scale = expf(mrun - mnew);
    float psum = 0.f;
#pragma unroll
    for (int mm = 0; mm < 4; mm++) {
      float p0 = expf(accS[mm][0] - mnew), p1 = expf(accS[mm][1] - mnew);
      float p2 = expf(accS[mm][2] - mnew), p3 = expf(accS[mm][3] - mnew);
      psum += (p0 + p1) + (p2 + p3);
      ushort4 pk;
      pk.x = f2bf(p0); pk.y = f2bf(p1); pk.z = f2bf(p2); pk.w = f2bf(p3);
      *(ushort4*)&Pl[w][(l & 15) * 72 + mm * 16 + (l >> 4) * 4] = pk;
    }
    psum += __shfl_xor(psum, 16);
    psum += __shfl_xor(psum, 32);
    lrun = lrun * scale + psum;
    mrun = mnew;
#pragma unroll
    for (int mm = 0; mm < 8; mm++) accO[mm] = accO[mm] * scale;
#pragma unroll
    for (int kc2 = 0; kc2 < 2; kc2++) {
      short8 bp = *(const short8*)((const char*)&Pl[w][0] + (l & 15) * 144 + kc2 * 64 + (l >> 4) * 16);
#pragma unroll
      for (int mm = 0; mm < 8; mm++) {
        int rowd = mm * 16 + (l & 15);
        int logb = rowd * 128 + kc2 * 64 + (l >> 4) * 16;
        int phys = logb ^ ((rowd & 7) << 4);
        short8 av = *(const short8*)((const char*)Vl + phys);
        accO[mm] = __builtin_amdgcn_mfma_f32_16x16x32_bf16(av, bp, accO[mm], 0, 0, 0);
      }
    }
    __syncthreads();
  }
  float rinv = 1.f / lrun;
#pragma unroll
  for (int mm = 0; mm < 8; mm++) {
    ushort4 pk;
    pk.x = f2bf(accO[mm][0] * rinv); pk.y = f2bf(accO[mm][1] * rinv);
    pk.z = f2bf(accO[mm][2] * rinv); pk.w = f2bf(accO[mm][3] * rinv);
    *(ushort4*)&out[(size_t)qrow * 4096 + hd * 128 + mm * 16 + (l >> 4) * 4] = pk;
  }
}

// ---------- silu-mul on fused x1x3 [2048][22016]: x1 *= silu(x3) in place ----------
__global__ __launch_bounds__(256) void silumul_kernel(u16* __restrict__ x1x3) {
  int cg = blockIdx.x * 256 + threadIdx.x;
  if (cg >= 1376) return;
  size_t base = (size_t)blockIdx.y * 22016 + cg * 8;
  uint4 a = *(const uint4*)&x1x3[base];
  uint4 b = *(const uint4*)&x1x3[base + 11008];
  unsigned int* ap = (unsigned int*)&a;
  const unsigned int* bp = (const unsigned int*)&b;
#pragma unroll
  for (int j = 0; j < 4; j++) {
    float a0 = bf2f(ap[j] & 0xffff), a1 = bf2f(ap[j] >> 16);
    float b0 = bf2f(bp[j] & 0xffff), b1 = bf2f(bp[j] >> 16);
    float r0 = a0 * (b0 / (1.f + expf(-b0)));
    float r1 = a1 * (b1 / (1.f + expf(-b1)));
    ap[j] = (unsigned int)f2bf(r0) | ((unsigned int)f2bf(r1) << 16);
  }
  *(uint4*)&x1x3[base] = a;
}

// ---------- launch ----------
extern "C" void kernel_launch(void* const* d_in, const int* in_sizes, int n_in,
                              void* d_out, int out_size, void* d_ws, size_t ws_size,
                              hipStream_t stream) {
  const float* x      = (const float*)d_in[0];
  const float* wq     = (const float*)d_in[1];
  const float* wk     = (const float*)d_in[2];
  const float* wv     = (const float*)d_in[3];
  const float* wo     = (const float*)d_in[4];
  const float* w1     = (const float*)d_in[5];
  const float* w2     = (const float*)d_in[6];
  const float* w3     = (const float*)d_in[7];
  const float* g_attn = (const float*)d_in[8];
  const float* g_ffn  = (const float*)d_in[9];

  char* ws = (char*)d_ws;
  // region layout (total ~383 MB)
  char* R0 = ws;                                   // 180.4MB rotating weights (hi)
  char* R1 = R0 + (size_t)22016 * 4096 * 2;        // 67.1MB wqk_lo; later xo,h2
  char* R2 = R1 + (size_t)8192 * 4096 * 2;         // 33.6MB h_hi,h_lo
  char* R3 = R2 + (size_t)2 * 2048 * 4096 * 2;     // 67.1MB qk hi/lo; later x1x3 (spans R4)
  char* R4 = R3 + (size_t)2 * 2048 * 8192 * 2;     // 33.6MB v,vT; ao over v
  char* RT = R4 + (size_t)2 * 2048 * 4096 * 2;     // 1MB rope table
  (void)ws_size; (void)in_sizes; (void)n_in; (void)out_size;

  u16* wA    = (u16*)R0;
  u16* wB    = (u16*)R1;
  u16* h_hi  = (u16*)R2;
  u16* h_lo  = (u16*)(R2 + (size_t)2048 * 4096 * 2);
  u16* qk_hi = (u16*)R3;
  u16* qk_lo = (u16*)(R3 + (size_t)2048 * 8192 * 2);
  u16* v     = (u16*)R4;
  u16* vT    = (u16*)(R4 + (size_t)2048 * 4096 * 2);
  u16* ao    = (u16*)R4;                            // over v (dead after vtrans)
  float* xo  = (float*)R1;                          // wB dead after QK GEMM
  u16* h2    = (u16*)(R1 + (size_t)2048 * 4096 * 4);
  u16* x1x3  = (u16*)R3;                            // qk dead after attn; spans into R4
  float* tab = (float*)RT;

  dim3 tb(32, 8);
  dim3 g44(4096 / 32, 4096 / 32);

  rope_table_kernel<<<512, 256, 0, stream>>>(tab);
  rmsnorm_kernel<true><<<2048, 256, 0, stream>>>(x, g_attn, h_hi, h_lo);
  // fused Q|K projection: one plain GEMM over K'=12288 (TRIK split product)
  tconv_split_kernel<<<g44, tb, 0, stream>>>(wq, wA, wB, 4096, 4096);
  tconv_split_kernel<<<g44, tb, 0, stream>>>(wk, wA + (size_t)4096 * 4096, wB + (size_t)4096 * 4096, 4096, 4096);
  gemm8_kernel<2, true><<<dim3(32, 8), 512, 0, stream>>>(
      h_hi, h_lo, wA, wB, qk_hi, qk_lo, 2048, 8192, 12288, 4096, 4096);
  rope_inplace_kernel<<<32768, 256, 0, stream>>>(qk_hi, qk_lo, tab);
  // V projection (plain) : 128x256 tile, grid (16,16) = 256 blocks
  tconv_kernel<<<g44, tb, 0, stream>>>(wv, wA, 4096, 4096);
  gemm8n_kernel<1><<<dim3(16, 16), 512, 0, stream>>>(h_hi, wA, v, 2048, 4096, 4096, 4096, 4096);
  vtrans_kernel<<<dim3(64, 4, 32), tb, 0, stream>>>(v, vT);
  // attention
  attn_kernel<<<dim3(32, 32), 256, 0, stream>>>(qk_hi, qk_lo, qk_hi + 4096, qk_lo + 4096, vT, ao);
  // xo = ao @ wo (f32)
  tconv_kernel<<<g44, tb, 0, stream>>>(wo, wA, 4096, 4096);
  gemm8n_kernel<0><<<dim3(16, 16), 512, 0, stream>>>(ao, wA, xo, 2048, 4096, 4096, 4096, 4096);
  rmsnorm_kernel<false><<<2048, 256, 0, stream>>>(xo, g_ffn, h2, nullptr);
  // fused FFN up: x1|x3 = h2 @ [w1 w3]  (8-phase 256^2, N=22016)
  tconv_kernel<<<dim3(344, 128), tb, 0, stream>>>(w1, wA, 4096, 11008);
  tconv_kernel<<<dim3(344, 128), tb, 0, stream>>>(w3, wA + (size_t)11008 * 4096, 4096, 11008);
  gemm8_kernel<1, false><<<dim3(86, 8), 512, 0, stream>>>(
      h2, nullptr, wA, nullptr, x1x3, nullptr, 2048, 22016, 4096, 4096, 4096);
  silumul_kernel<<<dim3(6, 2048), 256, 0, stream>>>(x1x3);
  // out = (x1*silu(x3)) @ w2 : K=11008
  tconv_kernel<<<dim3(128, 344), tb, 0, stream>>>(w2, wA, 11008, 4096);
  gemm8n_kernel<0><<<dim3(16, 16), 512, 0, stream>>>(x1x3, wA, (float*)d_out, 2048, 4096, 11008, 22016, 11008);
}